// Round 12
// baseline (566.290 us; speedup 1.0000x reference)
//
#include <hip/hip_runtime.h>
#include <hip/hip_bf16.h>

#define NN 100000
#define NE 1600000
#define NB 196    // buckets of 512 nodes (node>>9)
#define BSH 9
#define SCH 4096  // edges per scatter chunk

typedef _Float16 f16;
typedef __attribute__((ext_vector_type(2))) _Float16 h2;
typedef __attribute__((ext_vector_type(8))) _Float16 f16x8;
typedef __attribute__((ext_vector_type(8))) short short8;
typedef __attribute__((ext_vector_type(4))) float f32x4;

__device__ __forceinline__ short f16b(float x) {
    f16 h = (f16)x; short s; __builtin_memcpy(&s, &h, 2); return s;
}
__device__ __forceinline__ int h2i(h2 v) { int r; __builtin_memcpy(&r, &v, 4); return r; }
__device__ __forceinline__ h2 i2h(int v) { h2 r; __builtin_memcpy(&r, &v, 4); return r; }

// ================= graph build: counting-sort CSR =================
__global__ __launch_bounds__(256) void hist_kernel(const int* __restrict__ src,
                                                   const int* __restrict__ dst,
                                                   int* __restrict__ binS,
                                                   int* __restrict__ binD, int E) {
    __shared__ int hS[NB], hD[NB];
    for (int i = threadIdx.x; i < NB; i += 256) { hS[i] = 0; hD[i] = 0; }
    __syncthreads();
    for (int e = blockIdx.x * 256 + threadIdx.x; e < E; e += gridDim.x * 256) {
        atomicAdd(&hS[src[e] >> BSH], 1);
        atomicAdd(&hD[dst[e] >> BSH], 1);
    }
    __syncthreads();
    for (int i = threadIdx.x; i < NB; i += 256) {
        if (hS[i]) atomicAdd(&binS[i], hS[i]);
        if (hD[i]) atomicAdd(&binD[i], hD[i]);
    }
}

__global__ void scan_kernel(const int* __restrict__ binS, const int* __restrict__ binD,
                            int* __restrict__ curS, int* __restrict__ offS,
                            int* __restrict__ curD, int* __restrict__ offD,
                            int* __restrict__ rowptr, int E) {
    if (threadIdx.x == 0 && blockIdx.x == 0) {
        int rs = 0, rd = 0;
        for (int i = 0; i < NB; ++i) {
            curS[i] = rs; offS[i] = rs; rs += binS[i];
            curD[i] = rd; offD[i] = rd; rd += binD[i];
        }
        offS[NB] = rs;
        offD[NB] = rd;
        rowptr[NN] = E;
    }
}

__global__ __launch_bounds__(256) void scatter_kernel(const int* __restrict__ src,
                                                      const int* __restrict__ dst,
                                                      int* __restrict__ curS,
                                                      int* __restrict__ curD,
                                                      int* __restrict__ srcB,
                                                      int* __restrict__ packB, int E) {
    __shared__ int cS[NB], cD[NB], bS[NB], bD[NB];
    int base = blockIdx.x * SCH;
    for (int i = threadIdx.x; i < NB; i += 256) { cS[i] = 0; cD[i] = 0; }
    __syncthreads();
    int s[16], d[16], rS[16], rD[16];
#pragma unroll
    for (int k = 0; k < 16; ++k) {
        int idx = base + k * 256 + threadIdx.x;
        if (idx < E) {
            s[k] = src[idx]; d[k] = dst[idx];
            rS[k] = atomicAdd(&cS[s[k] >> BSH], 1);
            rD[k] = atomicAdd(&cD[d[k] >> BSH], 1);
        } else {
            s[k] = -1;
        }
    }
    __syncthreads();
    for (int i = threadIdx.x; i < NB; i += 256) {
        if (cS[i]) bS[i] = atomicAdd(&curS[i], cS[i]);
        if (cD[i]) bD[i] = atomicAdd(&curD[i], cD[i]);
    }
    __syncthreads();
#pragma unroll
    for (int k = 0; k < 16; ++k) {
        if (s[k] >= 0) {
            srcB[bS[s[k] >> BSH] + rS[k]] = s[k];
            packB[bD[d[k] >> BSH] + rD[k]] = s[k] | ((d[k] & 511) << 20);
        }
    }
}

__global__ __launch_bounds__(256) void csr_kernel(const int* __restrict__ offD,
                                                  const int* __restrict__ packB,
                                                  int* __restrict__ rowptr,
                                                  int* __restrict__ csrCol, int n) {
    int b = blockIdx.x;
    int node0 = b << BSH;
    int nNodes = min(512, n - node0);
    if (nNodes <= 0) return;
    int beg = offD[b], end = offD[b + 1];
    __shared__ int h[512];
    __shared__ int roff[512];
    for (int i = threadIdx.x; i < 512; i += 256) h[i] = 0;
    __syncthreads();
    for (int p = beg + threadIdx.x; p < end; p += 256)
        atomicAdd(&h[(packB[p] >> 20) & 511], 1);
    __syncthreads();
    if (threadIdx.x == 0) {
        int r = beg;
        for (int i = 0; i < 512; ++i) { roff[i] = r; r += h[i]; }
    }
    __syncthreads();
    for (int i = threadIdx.x; i < nNodes; i += 256) rowptr[node0 + i] = roff[i];
    for (int i = threadIdx.x; i < 512; i += 256) h[i] = 0;
    __syncthreads();
    for (int p = beg + threadIdx.x; p < end; p += 256) {
        int pk = packB[p];
        int dl = (pk >> 20) & 511;
        int r = atomicAdd(&h[dl], 1);
        csrCol[roff[dl] + r] = pk & 0xFFFFF;
    }
}

__global__ __launch_bounds__(256) void deg_kernel(const int* __restrict__ offS,
                                                  const int* __restrict__ srcB,
                                                  float* __restrict__ dinv, int n) {
    int b = blockIdx.x;
    int node0 = b << BSH;
    int nNodes = min(512, n - node0);
    if (nNodes <= 0) return;
    int beg = offS[b], end = offS[b + 1];
    __shared__ int h[512];
    for (int i = threadIdx.x; i < 512; i += 256) h[i] = 0;
    __syncthreads();
    for (int p = beg + threadIdx.x; p < end; p += 256)
        atomicAdd(&h[srcB[p] & 511], 1);
    __syncthreads();
    for (int i = threadIdx.x; i < nNodes; i += 256) {
        int d = h[i];
        dinv[node0 + i] = d > 0 ? rsqrtf((float)d) : 0.0f;
    }
}

// ================= weight prep: Bt[j][k] over j = [W0-W2 | W1 | 2*W2] cols (fp16) ========
__global__ void convw_kernel(const float* __restrict__ W0, const float* __restrict__ W1,
                             const float* __restrict__ W2, short* __restrict__ Bt0,
                             short* __restrict__ Bt1, short* __restrict__ Bt2) {
    int i = blockIdx.x * blockDim.x + threadIdx.x;
    if (i < 49152) {                       // Bt0: 384 x 128
        int j = i >> 7, k = i & 127;
        int t = j >> 7, o = j & 127;
        float v = (t == 0) ? W0[k * 128 + o] - W0[2 * 16384 + k * 128 + o]
                : (t == 1) ? W0[16384 + k * 128 + o]
                           : 2.f * W0[2 * 16384 + k * 128 + o];
        Bt0[j * 128 + k] = f16b(v);
    } else if (i < 98304) {                // Bt1: 384 x 128
        int m = i - 49152;
        int j = m >> 7, k = m & 127;
        int t = j >> 7, o = j & 127;
        float v = (t == 0) ? W1[k * 128 + o] - W1[2 * 16384 + k * 128 + o]
                : (t == 1) ? W1[16384 + k * 128 + o]
                           : 2.f * W1[2 * 16384 + k * 128 + o];
        Bt1[j * 128 + k] = f16b(v);
    } else if (i < 122880) {               // Bt2: 192 x 128
        int m = i - 98304;
        int j = m >> 7, k = m & 127;
        int t = j >> 6, o = j & 63;
        float v = (t == 0) ? W2[k * 64 + o] - W2[2 * 8192 + k * 64 + o]
                : (t == 1) ? W2[8192 + k * 64 + o]
                           : 2.f * W2[2 * 8192 + k * 64 + o];
        Bt2[j * 128 + k] = f16b(v);
    }
}

// ================= copy x (fp32 [n][128]) -> xb sliced [2][n][64] fp16 =================
__global__ __launch_bounds__(256) void copyx_kernel(const float* __restrict__ x,
                                                    short* __restrict__ xb, int n) {
    int i = blockIdx.x * 256 + threadIdx.x;   // 8 channels per thread
    if (i < n * 16) {
        int row = i >> 4, ch8 = i & 15;
        int c = ch8 * 8;
        const float4* xp = (const float4*)(x + (size_t)row * 128 + c);
        float4 f0 = xp[0], f1 = xp[1];
        short8 v;
        v[0] = f16b(f0.x); v[1] = f16b(f0.y); v[2] = f16b(f0.z); v[3] = f16b(f0.w);
        v[4] = f16b(f1.x); v[5] = f16b(f1.y); v[6] = f16b(f1.z); v[7] = f16b(f1.w);
        *(short8*)(xb + ((size_t)(c >> 6) * n + row) * 64 + (c & 63)) = v;
    }
}

// ================= GEMM: [Y0|Y1|Y2] = A @ Bt^T + (bias into Y0), fp16 ===================
// A is sliced [2][n][64]. Outputs: C=128 -> sliced [2][n][64] slabs; C=64 -> [n][64].
template <int C>
__global__ __launch_bounds__(256) void gemm_kernel(const short* __restrict__ A,
                                                   const short* __restrict__ Bt,
                                                   const float* __restrict__ bias,
                                                   short* out0, short* out1, short* out2,
                                                   int n) {
    constexpr int BNT = 3 * C;         // 384 or 192
    constexpr int WC = BNT / 96;       // waves along N: 4 (C=128) or 2 (C=64)
    constexpr int WR = 4 / WC;         // waves along M: 1 or 2
    constexpr int WM = 64 / WR;        // 64 or 32
    constexpr int MF = WM / 16;        // 4 or 2
    constexpr int NF = 6;              // 96/16
    constexpr int LDP = 40;
    constexpr int BSLOT = BNT * 4;
    constexpr int BITER = BSLOT / 256;
    __shared__ short lds[(64 + BNT) * LDP];
    short* As = lds;
    short* Bs = lds + 64 * LDP;

    int tid = threadIdx.x;
    int lane = tid & 63;
    int wid = tid >> 6;
    int wy = wid / WC;
    int wx = wid % WC;
    int row0 = blockIdx.x * 64;
    int l15 = lane & 15;
    int kb = (lane >> 4) * 8;

    int ar = tid >> 2, aseg = tid & 3;
    int agr = row0 + ar;

    f32x4 acc[MF][NF];
#pragma unroll
    for (int i = 0; i < MF; ++i)
#pragma unroll
        for (int j = 0; j < NF; ++j) acc[i][j] = (f32x4){0.f, 0.f, 0.f, 0.f};

    for (int step = 0; step < 4; ++step) {
        int k0 = step * 32;
        int c = k0 + aseg * 8;
        short8 va = (agr < n)
            ? *(const short8*)(A + ((size_t)(c >> 6) * n + agr) * 64 + (c & 63))
            : (short8){0, 0, 0, 0, 0, 0, 0, 0};
        *(short8*)&As[ar * LDP + aseg * 8] = va;
#pragma unroll
        for (int i = 0; i < BITER; ++i) {
            int slot = tid + i * 256;
            int j = slot >> 2, seg = slot & 3;
            *(short8*)&Bs[j * LDP + seg * 8] =
                *(const short8*)(Bt + (size_t)j * 128 + k0 + seg * 8);
        }
        __syncthreads();
        f16x8 af[MF], bfr[NF];
#pragma unroll
        for (int mf = 0; mf < MF; ++mf)
            af[mf] = *(f16x8*)&As[(wy * WM + mf * 16 + l15) * LDP + kb];
#pragma unroll
        for (int nf = 0; nf < NF; ++nf)
            bfr[nf] = *(f16x8*)&Bs[(wx * 96 + nf * 16 + l15) * LDP + kb];
#pragma unroll
        for (int mf = 0; mf < MF; ++mf)
#pragma unroll
            for (int nf = 0; nf < NF; ++nf)
                acc[mf][nf] = __builtin_amdgcn_mfma_f32_16x16x32_f16(
                    af[mf], bfr[nf], acc[mf][nf], 0, 0, 0);
        __syncthreads();
    }

    // ---- epilogue: per-wave LDS staging -> coalesced int4 row stores ----
    float bb[NF];
#pragma unroll
    for (int nf = 0; nf < NF; ++nf) {
        int colc = wx * 96 + nf * 16 + l15;
        bb[nf] = (colc < C) ? bias[colc] : 0.f;
    }
    short* st = lds + wid * 1536;
#pragma unroll
    for (int mf = 0; mf < MF; ++mf) {
#pragma unroll
        for (int nf = 0; nf < NF; ++nf) {
#pragma unroll
            for (int r = 0; r < 4; ++r) {
                int fr = (lane >> 4) * 4 + r;
                st[fr * 96 + nf * 16 + l15] = f16b(acc[mf][nf][r] + bb[nf]);
            }
        }
#pragma unroll
        for (int u = 0; u < 3; ++u) {
            int unit = u * 64 + lane;       // 0..191
            int rr = unit / 12;             // local row 0..15
            int seg = unit - rr * 12;       // 16B segment
            int grow = row0 + wy * WM + mf * 16 + rr;
            int colc = wx * 96 + seg * 8;
            int t = colc / C, cc = colc - t * C;
            short* P = (t == 0) ? out0 : (t == 1) ? out1 : out2;
            if (grow < n) {
                size_t addr = (C == 128)
                    ? ((size_t)(cc >> 6) * n + grow) * 64 + (cc & 63)
                    : (size_t)grow * 64 + cc;
                *(int4*)&P[addr] = *(const int4*)&st[rr * 96 + seg * 8];
            }
        }
    }
}

// ================= sliced prop: 64-ch slice per XCD half =================
// G, Add, O are [2][n][64] fp16. slice = (blockIdx&7)>>2 -> XCD affinity.
template <int RELU>
__global__ __launch_bounds__(256) void propS_kernel(const short* __restrict__ G,
                                                    const short* __restrict__ Add,
                                                    short* __restrict__ O,
                                                    const int* __restrict__ rowptr,
                                                    const int* __restrict__ csrCol,
                                                    const float* __restrict__ dinv, int n) {
    int bid = blockIdx.x;
    int xcd = bid & 7;
    int slice = xcd >> 2;
    int chunk = (bid >> 3) * 4 + (xcd & 3);
    int wv = threadIdx.x >> 6;
    int lane = threadIdx.x & 63;
    int wid = chunk * 4 + wv;          // node
    if (wid >= n) return;
    int beg = rowptr[wid];
    int c = rowptr[wid + 1] - beg;
    int sg = lane >> 3;                // edge group 0..7
    int sl = lane & 7;                 // 8-ch sub-chunk
    const short* Gs = G + (size_t)slice * n * 64;
    h2 a0 = {0, 0}, a1 = {0, 0}, a2 = {0, 0}, a3 = {0, 0};
    for (int b0 = 0; b0 < c; b0 += 64) {
        int cb = min(64, c - b0);
        int myc = 0, mywp = 0;
        if (lane < cb) {
            myc = csrCol[beg + b0 + lane];
            f16 hw = (f16)dinv[myc];
            h2 p = {hw, hw};
            mywp = h2i(p);
        }
        for (int base = 0; base < cb; base += 32) {
            int j0 = base + sg, j1 = j0 + 8, j2 = j0 + 16, j3 = j0 + 24;
            int s0 = __shfl(myc, j0);  int w0 = __shfl(mywp, j0);
            int s1 = __shfl(myc, j1);  int w1 = __shfl(mywp, j1);
            int s2 = __shfl(myc, j2);  int w2 = __shfl(mywp, j2);
            int s3 = __shfl(myc, j3);  int w3 = __shfl(mywp, j3);
            int4 v0 = *(const int4*)(Gs + (size_t)s0 * 64 + sl * 8);
            int4 v1 = *(const int4*)(Gs + (size_t)s1 * 64 + sl * 8);
            int4 v2 = *(const int4*)(Gs + (size_t)s2 * 64 + sl * 8);
            int4 v3 = *(const int4*)(Gs + (size_t)s3 * 64 + sl * 8);
            h2 p0 = i2h(w0), p1 = i2h(w1), p2 = i2h(w2), p3 = i2h(w3);
            a0 = i2h(v0.x) * p0 + a0; a1 = i2h(v0.y) * p0 + a1;
            a2 = i2h(v0.z) * p0 + a2; a3 = i2h(v0.w) * p0 + a3;
            a0 = i2h(v1.x) * p1 + a0; a1 = i2h(v1.y) * p1 + a1;
            a2 = i2h(v1.z) * p1 + a2; a3 = i2h(v1.w) * p1 + a3;
            a0 = i2h(v2.x) * p2 + a0; a1 = i2h(v2.y) * p2 + a1;
            a2 = i2h(v2.z) * p2 + a2; a3 = i2h(v2.w) * p2 + a3;
            a0 = i2h(v3.x) * p3 + a0; a1 = i2h(v3.y) * p3 + a1;
            a2 = i2h(v3.z) * p3 + a2; a3 = i2h(v3.w) * p3 + a3;
        }
    }
#pragma unroll
    for (int off = 8; off < 64; off <<= 1) {
        a0 += i2h(__shfl_xor(h2i(a0), off));
        a1 += i2h(__shfl_xor(h2i(a1), off));
        a2 += i2h(__shfl_xor(h2i(a2), off));
        a3 += i2h(__shfl_xor(h2i(a3), off));
    }
    if (lane < 8) {
        float scale = -dinv[wid];
        size_t rb = ((size_t)slice * n + wid) * 64 + sl * 8;
        int4 ad = *(const int4*)(Add + rb);
        h2 d0 = i2h(ad.x), d1 = i2h(ad.y), d2 = i2h(ad.z), d3 = i2h(ad.w);
        float r0 = fmaf(scale, (float)a0[0], (float)d0[0]);
        float r1 = fmaf(scale, (float)a0[1], (float)d0[1]);
        float r2 = fmaf(scale, (float)a1[0], (float)d1[0]);
        float r3 = fmaf(scale, (float)a1[1], (float)d1[1]);
        float r4 = fmaf(scale, (float)a2[0], (float)d2[0]);
        float r5 = fmaf(scale, (float)a2[1], (float)d2[1]);
        float r6 = fmaf(scale, (float)a3[0], (float)d3[0]);
        float r7 = fmaf(scale, (float)a3[1], (float)d3[1]);
        if (RELU) {
            r0 = fmaxf(r0, 0.f); r1 = fmaxf(r1, 0.f); r2 = fmaxf(r2, 0.f);
            r3 = fmaxf(r3, 0.f); r4 = fmaxf(r4, 0.f); r5 = fmaxf(r5, 0.f);
            r6 = fmaxf(r6, 0.f); r7 = fmaxf(r7, 0.f);
        }
        int4 w;
        h2 o0 = {(f16)r0, (f16)r1}, o1 = {(f16)r2, (f16)r3};
        h2 o2 = {(f16)r4, (f16)r5}, o3 = {(f16)r6, (f16)r7};
        w.x = h2i(o0); w.y = h2i(o1); w.z = h2i(o2); w.w = h2i(o3);
        *(int4*)(O + rb) = w;
    }
}

// ================= unsliced C=64 prop (layer 3) =================
template <int RELU, int OUTF>
__global__ __launch_bounds__(256) void prop64_kernel(const short* __restrict__ G,
                                                     const short* __restrict__ Add,
                                                     void* __restrict__ O,
                                                     const int* __restrict__ rowptr,
                                                     const int* __restrict__ csrCol,
                                                     const float* __restrict__ dinv, int n) {
    int wid = (blockIdx.x * blockDim.x + threadIdx.x) >> 6;
    int lane = threadIdx.x & 63;
    if (wid >= n) return;
    int beg = rowptr[wid];
    int c = rowptr[wid + 1] - beg;
    int sg = lane >> 3;
    int sl = lane & 7;
    h2 a0 = {0, 0}, a1 = {0, 0}, a2 = {0, 0}, a3 = {0, 0};
    for (int b0 = 0; b0 < c; b0 += 64) {
        int cb = min(64, c - b0);
        int myc = 0, mywp = 0;
        if (lane < cb) {
            myc = csrCol[beg + b0 + lane];
            f16 hw = (f16)dinv[myc];
            h2 p = {hw, hw};
            mywp = h2i(p);
        }
        for (int base = 0; base < cb; base += 32) {
            int j0 = base + sg, j1 = j0 + 8, j2 = j0 + 16, j3 = j0 + 24;
            int s0 = __shfl(myc, j0);  int w0 = __shfl(mywp, j0);
            int s1 = __shfl(myc, j1);  int w1 = __shfl(mywp, j1);
            int s2 = __shfl(myc, j2);  int w2 = __shfl(mywp, j2);
            int s3 = __shfl(myc, j3);  int w3 = __shfl(mywp, j3);
            int4 v0 = *(const int4*)(G + (size_t)s0 * 64 + sl * 8);
            int4 v1 = *(const int4*)(G + (size_t)s1 * 64 + sl * 8);
            int4 v2 = *(const int4*)(G + (size_t)s2 * 64 + sl * 8);
            int4 v3 = *(const int4*)(G + (size_t)s3 * 64 + sl * 8);
            h2 p0 = i2h(w0), p1 = i2h(w1), p2 = i2h(w2), p3 = i2h(w3);
            a0 = i2h(v0.x) * p0 + a0; a1 = i2h(v0.y) * p0 + a1;
            a2 = i2h(v0.z) * p0 + a2; a3 = i2h(v0.w) * p0 + a3;
            a0 = i2h(v1.x) * p1 + a0; a1 = i2h(v1.y) * p1 + a1;
            a2 = i2h(v1.z) * p1 + a2; a3 = i2h(v1.w) * p1 + a3;
            a0 = i2h(v2.x) * p2 + a0; a1 = i2h(v2.y) * p2 + a1;
            a2 = i2h(v2.z) * p2 + a2; a3 = i2h(v2.w) * p2 + a3;
            a0 = i2h(v3.x) * p3 + a0; a1 = i2h(v3.y) * p3 + a1;
            a2 = i2h(v3.z) * p3 + a2; a3 = i2h(v3.w) * p3 + a3;
        }
    }
#pragma unroll
    for (int off = 8; off < 64; off <<= 1) {
        a0 += i2h(__shfl_xor(h2i(a0), off));
        a1 += i2h(__shfl_xor(h2i(a1), off));
        a2 += i2h(__shfl_xor(h2i(a2), off));
        a3 += i2h(__shfl_xor(h2i(a3), off));
    }
    if (lane < 8) {
        float scale = -dinv[wid];
        int4 ad = *(const int4*)(Add + (size_t)wid * 64 + sl * 8);
        h2 d0 = i2h(ad.x), d1 = i2h(ad.y), d2 = i2h(ad.z), d3 = i2h(ad.w);
        float r0 = fmaf(scale, (float)a0[0], (float)d0[0]);
        float r1 = fmaf(scale, (float)a0[1], (float)d0[1]);
        float r2 = fmaf(scale, (float)a1[0], (float)d1[0]);
        float r3 = fmaf(scale, (float)a1[1], (float)d1[1]);
        float r4 = fmaf(scale, (float)a2[0], (float)d2[0]);
        float r5 = fmaf(scale, (float)a2[1], (float)d2[1]);
        float r6 = fmaf(scale, (float)a3[0], (float)d3[0]);
        float r7 = fmaf(scale, (float)a3[1], (float)d3[1]);
        if (RELU) {
            r0 = fmaxf(r0, 0.f); r1 = fmaxf(r1, 0.f); r2 = fmaxf(r2, 0.f);
            r3 = fmaxf(r3, 0.f); r4 = fmaxf(r4, 0.f); r5 = fmaxf(r5, 0.f);
            r6 = fmaxf(r6, 0.f); r7 = fmaxf(r7, 0.f);
        }
        if (OUTF) {
            float* op = (float*)O + (size_t)wid * 64 + sl * 8;
            *(float4*)op = make_float4(r0, r1, r2, r3);
            *(float4*)(op + 4) = make_float4(r4, r5, r6, r7);
        } else {
            int4 w;
            h2 o0 = {(f16)r0, (f16)r1}, o1 = {(f16)r2, (f16)r3};
            h2 o2 = {(f16)r4, (f16)r5}, o3 = {(f16)r6, (f16)r7};
            w.x = h2i(o0); w.y = h2i(o1); w.z = h2i(o2); w.w = h2i(o3);
            *(int4*)((short*)O + (size_t)wid * 64 + sl * 8) = w;
        }
    }
}

extern "C" void kernel_launch(void* const* d_in, const int* in_sizes, int n_in,
                              void* d_out, int out_size, void* d_ws, size_t ws_size,
                              hipStream_t stream) {
    const float* x  = (const float*)d_in[0];
    const int*   ei = (const int*)d_in[1];
    const float* W0 = (const float*)d_in[2];
    const float* b0 = (const float*)d_in[3];
    const float* W1 = (const float*)d_in[4];
    const float* b1 = (const float*)d_in[5];
    const float* W2 = (const float*)d_in[6];
    const float* b2 = (const float*)d_in[7];
    float* out = (float*)d_out;

    const int n = NN, E = NE;
    const int* src = ei;
    const int* dst = ei + E;

    char* ws = (char*)d_ws;
    auto alloc = [&](size_t bytes) -> void* {
        void* p = (void*)ws;
        ws += (bytes + 255) & ~(size_t)255;
        return p;
    };
    int*   binS   = (int*)alloc(NB * 4);
    int*   binD   = (int*)alloc(NB * 4);
    int*   curS   = (int*)alloc((NB + 1) * 4);
    int*   offS   = (int*)alloc((NB + 1) * 4);
    int*   curD   = (int*)alloc((NB + 1) * 4);
    int*   offD   = (int*)alloc((NB + 1) * 4);
    int*   srcB   = (int*)alloc((size_t)E * 4);
    int*   packB  = (int*)alloc((size_t)E * 4);
    int*   rowptr = (int*)alloc((size_t)(n + 1) * 4);
    int*   csrCol = (int*)alloc((size_t)E * 4);
    float* dinv   = (float*)alloc((size_t)n * 4);
    short* xb     = (short*)alloc((size_t)n * 128 * 2);
    short* buf0   = (short*)alloc((size_t)n * 128 * 2);
    short* buf1   = (short*)alloc((size_t)n * 128 * 2);
    short* buf2   = (short*)alloc((size_t)n * 128 * 2);
    short* buf3   = (short*)alloc((size_t)n * 128 * 2);
    short* Bt0    = (short*)alloc((size_t)384 * 128 * 2);
    short* Bt1    = (short*)alloc((size_t)384 * 128 * 2);
    short* Bt2    = (short*)alloc((size_t)192 * 128 * 2);

    hipMemsetAsync(binS, 0, NB * 4, stream);
    hipMemsetAsync(binD, 0, NB * 4, stream);

    const int TPB = 256;

    hist_kernel<<<256, TPB, 0, stream>>>(src, dst, binS, binD, E);
    scan_kernel<<<1, 64, 0, stream>>>(binS, binD, curS, offS, curD, offD, rowptr, E);
    int sChunks = (E + SCH - 1) / SCH;
    scatter_kernel<<<sChunks, TPB, 0, stream>>>(src, dst, curS, curD, srcB, packB, E);
    csr_kernel<<<NB, TPB, 0, stream>>>(offD, packB, rowptr, csrCol, n);
    deg_kernel<<<NB, TPB, 0, stream>>>(offS, srcB, dinv, n);

    convw_kernel<<<(122880 + 255) / 256, 256, 0, stream>>>(W0, W1, W2, Bt0, Bt1, Bt2);
    copyx_kernel<<<(n * 16 + 255) / 256, 256, 0, stream>>>(x, xb, n);

    int gBlocks = (n + 63) / 64;                 // BM=64
    int chunksPerSlice = (n + 3) / 4;            // 4 nodes per chunk
    int sBlocksP = ((chunksPerSlice + 3) / 4) * 8;  // sliced prop grid
    int pBlocks64 = (n + 3) / 4;                 // unsliced C=64 prop

    // ---- layer 1 ----
    gemm_kernel<128><<<gBlocks, 256, 0, stream>>>(xb, Bt0, b0, buf0, buf1, buf2, n);
    propS_kernel<0><<<sBlocksP, 256, 0, stream>>>(buf2, buf1, buf3, rowptr, csrCol, dinv, n);
    propS_kernel<1><<<sBlocksP, 256, 0, stream>>>(buf3, buf0, buf1, rowptr, csrCol, dinv, n);
    // ---- layer 2 (Y1 in-place into buf1: own-block rows; safe) ----
    gemm_kernel<128><<<gBlocks, 256, 0, stream>>>(buf1, Bt1, b1, buf0, buf1, buf2, n);
    propS_kernel<0><<<sBlocksP, 256, 0, stream>>>(buf2, buf1, buf3, rowptr, csrCol, dinv, n);
    propS_kernel<1><<<sBlocksP, 256, 0, stream>>>(buf3, buf0, buf1, rowptr, csrCol, dinv, n);
    // ---- layer 3: C = 64 (unsliced) ----
    gemm_kernel<64><<<gBlocks, 256, 0, stream>>>(buf1, Bt2, b2, buf0, buf3, buf2, n);
    prop64_kernel<0, 0><<<pBlocks64, 256, 0, stream>>>(buf2, buf3, buf0 + (size_t)n * 64,
                                                       rowptr, csrCol, dinv, n);
    prop64_kernel<0, 1><<<pBlocks64, 256, 0, stream>>>(buf0 + (size_t)n * 64, buf0, out,
                                                       rowptr, csrCol, dinv, n);
}

// Round 13
// 514.016 us; speedup vs baseline: 1.1017x; 1.1017x over previous
//
#include <hip/hip_runtime.h>
#include <hip/hip_bf16.h>

#define NN 100000
#define NE 1600000
#define NB 196    // buckets of 512 nodes (node>>9)
#define BSH 9
#define SCH 2048  // edges per scatter chunk (782 blocks)

typedef _Float16 f16;
typedef __attribute__((ext_vector_type(2))) _Float16 h2;
typedef __attribute__((ext_vector_type(8))) _Float16 f16x8;
typedef __attribute__((ext_vector_type(8))) short short8;
typedef __attribute__((ext_vector_type(4))) float f32x4;

__device__ __forceinline__ short f16b(float x) {
    f16 h = (f16)x; short s; __builtin_memcpy(&s, &h, 2); return s;
}
__device__ __forceinline__ int h2i(h2 v) { int r; __builtin_memcpy(&r, &v, 4); return r; }
__device__ __forceinline__ h2 i2h(int v) { h2 r; __builtin_memcpy(&r, &v, 4); return r; }

// ================= graph build: counting-sort CSR =================
__global__ __launch_bounds__(256) void hist_kernel(const int* __restrict__ src,
                                                   const int* __restrict__ dst,
                                                   int* __restrict__ binS,
                                                   int* __restrict__ binD, int E) {
    __shared__ int hS[NB], hD[NB];
    for (int i = threadIdx.x; i < NB; i += 256) { hS[i] = 0; hD[i] = 0; }
    __syncthreads();
    for (int e = blockIdx.x * 256 + threadIdx.x; e < E; e += gridDim.x * 256) {
        atomicAdd(&hS[src[e] >> BSH], 1);
        atomicAdd(&hD[dst[e] >> BSH], 1);
    }
    __syncthreads();
    for (int i = threadIdx.x; i < NB; i += 256) {
        if (hS[i]) atomicAdd(&binS[i], hS[i]);
        if (hD[i]) atomicAdd(&binD[i], hD[i]);
    }
}

__global__ void scan_kernel(const int* __restrict__ binS, const int* __restrict__ binD,
                            int* __restrict__ curS, int* __restrict__ offS,
                            int* __restrict__ curD, int* __restrict__ offD,
                            int* __restrict__ rowptr, int E) {
    if (threadIdx.x == 0 && blockIdx.x == 0) {
        int rs = 0, rd = 0;
        for (int i = 0; i < NB; ++i) {
            curS[i] = rs; offS[i] = rs; rs += binS[i];
            curD[i] = rd; offD[i] = rd; rd += binD[i];
        }
        offS[NB] = rs;
        offD[NB] = rd;
        rowptr[NN] = E;
    }
}

__global__ __launch_bounds__(256) void scatter_kernel(const int* __restrict__ src,
                                                      const int* __restrict__ dst,
                                                      int* __restrict__ curS,
                                                      int* __restrict__ curD,
                                                      int* __restrict__ srcB,
                                                      int* __restrict__ packB, int E) {
    __shared__ int cS[NB], cD[NB], bS[NB], bD[NB];
    int base = blockIdx.x * SCH;
    for (int i = threadIdx.x; i < NB; i += 256) { cS[i] = 0; cD[i] = 0; }
    __syncthreads();
    int s[8], d[8], rS[8], rD[8];
#pragma unroll
    for (int k = 0; k < 8; ++k) {
        int idx = base + k * 256 + threadIdx.x;
        if (idx < E) {
            s[k] = src[idx]; d[k] = dst[idx];
            rS[k] = atomicAdd(&cS[s[k] >> BSH], 1);
            rD[k] = atomicAdd(&cD[d[k] >> BSH], 1);
        } else {
            s[k] = -1;
        }
    }
    __syncthreads();
    for (int i = threadIdx.x; i < NB; i += 256) {
        if (cS[i]) bS[i] = atomicAdd(&curS[i], cS[i]);
        if (cD[i]) bD[i] = atomicAdd(&curD[i], cD[i]);
    }
    __syncthreads();
#pragma unroll
    for (int k = 0; k < 8; ++k) {
        if (s[k] >= 0) {
            srcB[bS[s[k] >> BSH] + rS[k]] = s[k];
            packB[bD[d[k] >> BSH] + rD[k]] = s[k] | ((d[k] & 511) << 20);
        }
    }
}

__global__ __launch_bounds__(256) void csr_kernel(const int* __restrict__ offD,
                                                  const int* __restrict__ packB,
                                                  int* __restrict__ rowptr,
                                                  int* __restrict__ csrCol, int n) {
    int b = blockIdx.x;
    int node0 = b << BSH;
    int nNodes = min(512, n - node0);
    if (nNodes <= 0) return;
    int beg = offD[b], end = offD[b + 1];
    __shared__ int h[512];
    __shared__ int roff[512];
    for (int i = threadIdx.x; i < 512; i += 256) h[i] = 0;
    __syncthreads();
    for (int p = beg + threadIdx.x; p < end; p += 256)
        atomicAdd(&h[(packB[p] >> 20) & 511], 1);
    __syncthreads();
    if (threadIdx.x == 0) {
        int r = beg;
        for (int i = 0; i < 512; ++i) { roff[i] = r; r += h[i]; }
    }
    __syncthreads();
    for (int i = threadIdx.x; i < nNodes; i += 256) rowptr[node0 + i] = roff[i];
    for (int i = threadIdx.x; i < 512; i += 256) h[i] = 0;
    __syncthreads();
    for (int p = beg + threadIdx.x; p < end; p += 256) {
        int pk = packB[p];
        int dl = (pk >> 20) & 511;
        int r = atomicAdd(&h[dl], 1);
        csrCol[roff[dl] + r] = pk & 0xFFFFF;
    }
}

__global__ __launch_bounds__(256) void deg_kernel(const int* __restrict__ offS,
                                                  const int* __restrict__ srcB,
                                                  float* __restrict__ dinv, int n) {
    int b = blockIdx.x;
    int node0 = b << BSH;
    int nNodes = min(512, n - node0);
    if (nNodes <= 0) return;
    int beg = offS[b], end = offS[b + 1];
    __shared__ int h[512];
    for (int i = threadIdx.x; i < 512; i += 256) h[i] = 0;
    __syncthreads();
    for (int p = beg + threadIdx.x; p < end; p += 256)
        atomicAdd(&h[srcB[p] & 511], 1);
    __syncthreads();
    for (int i = threadIdx.x; i < nNodes; i += 256) {
        int d = h[i];
        dinv[node0 + i] = d > 0 ? rsqrtf((float)d) : 0.0f;
    }
}

// ================= weight prep: Bt[j][k] over j = [W0-W2 | W1 | 2*W2] cols (fp16) ========
__global__ void convw_kernel(const float* __restrict__ W0, const float* __restrict__ W1,
                             const float* __restrict__ W2, short* __restrict__ Bt0,
                             short* __restrict__ Bt1, short* __restrict__ Bt2) {
    int i = blockIdx.x * blockDim.x + threadIdx.x;
    if (i < 49152) {                       // Bt0: 384 x 128
        int j = i >> 7, k = i & 127;
        int t = j >> 7, o = j & 127;
        float v = (t == 0) ? W0[k * 128 + o] - W0[2 * 16384 + k * 128 + o]
                : (t == 1) ? W0[16384 + k * 128 + o]
                           : 2.f * W0[2 * 16384 + k * 128 + o];
        Bt0[j * 128 + k] = f16b(v);
    } else if (i < 98304) {                // Bt1: 384 x 128
        int m = i - 49152;
        int j = m >> 7, k = m & 127;
        int t = j >> 7, o = j & 127;
        float v = (t == 0) ? W1[k * 128 + o] - W1[2 * 16384 + k * 128 + o]
                : (t == 1) ? W1[16384 + k * 128 + o]
                           : 2.f * W1[2 * 16384 + k * 128 + o];
        Bt1[j * 128 + k] = f16b(v);
    } else if (i < 122880) {               // Bt2: 192 x 128
        int m = i - 98304;
        int j = m >> 7, k = m & 127;
        int t = j >> 6, o = j & 63;
        float v = (t == 0) ? W2[k * 64 + o] - W2[2 * 8192 + k * 64 + o]
                : (t == 1) ? W2[8192 + k * 64 + o]
                           : 2.f * W2[2 * 8192 + k * 64 + o];
        Bt2[j * 128 + k] = f16b(v);
    }
}

// ================= GEMM: [Y0|Y1|Y2] = A[n,128] @ Bt^T + (bias into Y0), fp16 ============
// 256 threads (4 waves), BM=64, K=128 (4 steps of BK=32). AF32=1: A is fp32, convert
// at ds_write time (no cross-barrier register holding).
template <int C, int AF32>
__global__ __launch_bounds__(256) void gemm_kernel(const void* __restrict__ A,
                                                   const short* __restrict__ Bt,
                                                   const float* __restrict__ bias,
                                                   short* out0, short* out1, short* out2,
                                                   int n) {
    constexpr int BNT = 3 * C;         // 384 or 192
    constexpr int WC = BNT / 96;       // waves along N: 4 (C=128) or 2 (C=64)
    constexpr int WR = 4 / WC;         // waves along M: 1 or 2
    constexpr int WM = 64 / WR;        // 64 or 32
    constexpr int MF = WM / 16;        // 4 or 2
    constexpr int NF = 6;              // 96/16
    constexpr int LDP = 40;
    constexpr int BSLOT = BNT * 4;
    constexpr int BITER = BSLOT / 256;
    __shared__ short lds[(64 + BNT) * LDP];
    short* As = lds;
    short* Bs = lds + 64 * LDP;

    int tid = threadIdx.x;
    int lane = tid & 63;
    int wid = tid >> 6;
    int wy = wid / WC;
    int wx = wid % WC;
    int row0 = blockIdx.x * 64;
    int l15 = lane & 15;
    int kb = (lane >> 4) * 8;

    int ar = tid >> 2, aseg = tid & 3;
    int agr = row0 + ar;

    f32x4 acc[MF][NF];
#pragma unroll
    for (int i = 0; i < MF; ++i)
#pragma unroll
        for (int j = 0; j < NF; ++j) acc[i][j] = (f32x4){0.f, 0.f, 0.f, 0.f};

    for (int step = 0; step < 4; ++step) {
        int k0 = step * 32;
        short8 va;
        if (AF32) {
            if (agr < n) {
                const float* xp = (const float*)A + (size_t)agr * 128 + k0 + aseg * 8;
                float4 f0 = *(const float4*)xp;
                float4 f1 = *(const float4*)(xp + 4);
                va[0] = f16b(f0.x); va[1] = f16b(f0.y); va[2] = f16b(f0.z); va[3] = f16b(f0.w);
                va[4] = f16b(f1.x); va[5] = f16b(f1.y); va[6] = f16b(f1.z); va[7] = f16b(f1.w);
            } else {
                va = (short8){0, 0, 0, 0, 0, 0, 0, 0};
            }
        } else {
            va = (agr < n)
                ? *(const short8*)((const short*)A + (size_t)agr * 128 + k0 + aseg * 8)
                : (short8){0, 0, 0, 0, 0, 0, 0, 0};
        }
        *(short8*)&As[ar * LDP + aseg * 8] = va;
#pragma unroll
        for (int i = 0; i < BITER; ++i) {
            int slot = tid + i * 256;
            int j = slot >> 2, seg = slot & 3;
            *(short8*)&Bs[j * LDP + seg * 8] =
                *(const short8*)(Bt + (size_t)j * 128 + k0 + seg * 8);
        }
        __syncthreads();
        f16x8 af[MF], bfr[NF];
#pragma unroll
        for (int mf = 0; mf < MF; ++mf)
            af[mf] = *(f16x8*)&As[(wy * WM + mf * 16 + l15) * LDP + kb];
#pragma unroll
        for (int nf = 0; nf < NF; ++nf)
            bfr[nf] = *(f16x8*)&Bs[(wx * 96 + nf * 16 + l15) * LDP + kb];
#pragma unroll
        for (int mf = 0; mf < MF; ++mf)
#pragma unroll
            for (int nf = 0; nf < NF; ++nf)
                acc[mf][nf] = __builtin_amdgcn_mfma_f32_16x16x32_f16(
                    af[mf], bfr[nf], acc[mf][nf], 0, 0, 0);
        __syncthreads();
    }

    // ---- epilogue: per-wave LDS staging -> coalesced int4 row stores ----
    float bb[NF];
#pragma unroll
    for (int nf = 0; nf < NF; ++nf) {
        int colc = wx * 96 + nf * 16 + l15;
        bb[nf] = (colc < C) ? bias[colc] : 0.f;
    }
    short* st = lds + wid * 1536;
#pragma unroll
    for (int mf = 0; mf < MF; ++mf) {
#pragma unroll
        for (int nf = 0; nf < NF; ++nf) {
#pragma unroll
            for (int r = 0; r < 4; ++r) {
                int fr = (lane >> 4) * 4 + r;
                st[fr * 96 + nf * 16 + l15] = f16b(acc[mf][nf][r] + bb[nf]);
            }
        }
#pragma unroll
        for (int u = 0; u < 3; ++u) {
            int unit = u * 64 + lane;       // 0..191
            int rr = unit / 12;             // local row 0..15
            int seg = unit - rr * 12;       // 16B segment
            int grow = row0 + wy * WM + mf * 16 + rr;
            int colc = wx * 96 + seg * 8;
            int t = colc / C, off = colc - t * C;
            short* P = (t == 0) ? out0 : (t == 1) ? out1 : out2;
            if (grow < n)
                *(int4*)&P[(size_t)grow * C + off] = *(const int4*)&st[rr * 96 + seg * 8];
        }
    }
}

// ================= prop: O[d] = act(Add[d] - dinv[d] * sum_e dinv[s]*G[s]), packed fp16 ==
template <int C, int RELU, int OUTF>
__global__ __launch_bounds__(256) void prop_kernel(const short* __restrict__ G,
                                                   const short* __restrict__ Add,
                                                   void* __restrict__ O,
                                                   const int* __restrict__ rowptr,
                                                   const int* __restrict__ csrCol,
                                                   const float* __restrict__ dinv, int n) {
    constexpr int LPE = C / 8;        // lanes per edge-row (16 or 8)
    constexpr int EPG = 64 / LPE;     // edges per load group (4 or 8)
    constexpr int STEP = 4 * EPG;     // edges per inner iter
    int wid = (blockIdx.x * blockDim.x + threadIdx.x) >> 6;
    int lane = threadIdx.x & 63;
    if (wid >= n) return;
    int beg = rowptr[wid];
    int c = rowptr[wid + 1] - beg;
    int sg = lane / LPE;
    int sl = lane & (LPE - 1);
    h2 a0 = {0, 0}, a1 = {0, 0}, a2 = {0, 0}, a3 = {0, 0};
    for (int b0 = 0; b0 < c; b0 += 64) {
        int cb = min(64, c - b0);
        int myc = 0, mywp = 0;
        if (lane < cb) {
            myc = csrCol[beg + b0 + lane];
            f16 hw = (f16)dinv[myc];
            h2 p = {hw, hw};
            mywp = h2i(p);
        }
        for (int base = 0; base < cb; base += STEP) {
            int j0 = base + sg, j1 = j0 + EPG, j2 = j0 + 2 * EPG, j3 = j0 + 3 * EPG;
            int s0 = __shfl(myc, j0);  int w0 = __shfl(mywp, j0);
            int s1 = __shfl(myc, j1);  int w1 = __shfl(mywp, j1);
            int s2 = __shfl(myc, j2);  int w2 = __shfl(mywp, j2);
            int s3 = __shfl(myc, j3);  int w3 = __shfl(mywp, j3);
            int4 v0 = *(const int4*)(G + (size_t)s0 * C + sl * 8);
            int4 v1 = *(const int4*)(G + (size_t)s1 * C + sl * 8);
            int4 v2 = *(const int4*)(G + (size_t)s2 * C + sl * 8);
            int4 v3 = *(const int4*)(G + (size_t)s3 * C + sl * 8);
            h2 p0 = i2h(w0), p1 = i2h(w1), p2 = i2h(w2), p3 = i2h(w3);
            a0 = i2h(v0.x) * p0 + a0; a1 = i2h(v0.y) * p0 + a1;
            a2 = i2h(v0.z) * p0 + a2; a3 = i2h(v0.w) * p0 + a3;
            a0 = i2h(v1.x) * p1 + a0; a1 = i2h(v1.y) * p1 + a1;
            a2 = i2h(v1.z) * p1 + a2; a3 = i2h(v1.w) * p1 + a3;
            a0 = i2h(v2.x) * p2 + a0; a1 = i2h(v2.y) * p2 + a1;
            a2 = i2h(v2.z) * p2 + a2; a3 = i2h(v2.w) * p2 + a3;
            a0 = i2h(v3.x) * p3 + a0; a1 = i2h(v3.y) * p3 + a1;
            a2 = i2h(v3.z) * p3 + a2; a3 = i2h(v3.w) * p3 + a3;
        }
    }
#pragma unroll
    for (int off = LPE; off < 64; off <<= 1) {
        a0 += i2h(__shfl_xor(h2i(a0), off));
        a1 += i2h(__shfl_xor(h2i(a1), off));
        a2 += i2h(__shfl_xor(h2i(a2), off));
        a3 += i2h(__shfl_xor(h2i(a3), off));
    }
    if (lane < LPE) {
        float scale = -dinv[wid];
        int4 ad = *(const int4*)(Add + (size_t)wid * C + sl * 8);
        h2 d0 = i2h(ad.x), d1 = i2h(ad.y), d2 = i2h(ad.z), d3 = i2h(ad.w);
        float r0 = fmaf(scale, (float)a0[0], (float)d0[0]);
        float r1 = fmaf(scale, (float)a0[1], (float)d0[1]);
        float r2 = fmaf(scale, (float)a1[0], (float)d1[0]);
        float r3 = fmaf(scale, (float)a1[1], (float)d1[1]);
        float r4 = fmaf(scale, (float)a2[0], (float)d2[0]);
        float r5 = fmaf(scale, (float)a2[1], (float)d2[1]);
        float r6 = fmaf(scale, (float)a3[0], (float)d3[0]);
        float r7 = fmaf(scale, (float)a3[1], (float)d3[1]);
        if (RELU) {
            r0 = fmaxf(r0, 0.f); r1 = fmaxf(r1, 0.f); r2 = fmaxf(r2, 0.f);
            r3 = fmaxf(r3, 0.f); r4 = fmaxf(r4, 0.f); r5 = fmaxf(r5, 0.f);
            r6 = fmaxf(r6, 0.f); r7 = fmaxf(r7, 0.f);
        }
        if (OUTF) {
            float* op = (float*)O + (size_t)wid * C + sl * 8;
            *(float4*)op = make_float4(r0, r1, r2, r3);
            *(float4*)(op + 4) = make_float4(r4, r5, r6, r7);
        } else {
            int4 w;
            h2 o0 = {(f16)r0, (f16)r1}, o1 = {(f16)r2, (f16)r3};
            h2 o2 = {(f16)r4, (f16)r5}, o3 = {(f16)r6, (f16)r7};
            w.x = h2i(o0); w.y = h2i(o1); w.z = h2i(o2); w.w = h2i(o3);
            *(int4*)((short*)O + (size_t)wid * C + sl * 8) = w;
        }
    }
}

extern "C" void kernel_launch(void* const* d_in, const int* in_sizes, int n_in,
                              void* d_out, int out_size, void* d_ws, size_t ws_size,
                              hipStream_t stream) {
    const float* x  = (const float*)d_in[0];
    const int*   ei = (const int*)d_in[1];
    const float* W0 = (const float*)d_in[2];
    const float* b0 = (const float*)d_in[3];
    const float* W1 = (const float*)d_in[4];
    const float* b1 = (const float*)d_in[5];
    const float* W2 = (const float*)d_in[6];
    const float* b2 = (const float*)d_in[7];
    float* out = (float*)d_out;

    const int n = NN, E = NE;
    const int* src = ei;
    const int* dst = ei + E;

    char* ws = (char*)d_ws;
    auto alloc = [&](size_t bytes) -> void* {
        void* p = (void*)ws;
        ws += (bytes + 255) & ~(size_t)255;
        return p;
    };
    int*   binS   = (int*)alloc(NB * 4);
    int*   binD   = (int*)alloc(NB * 4);
    int*   curS   = (int*)alloc((NB + 1) * 4);
    int*   offS   = (int*)alloc((NB + 1) * 4);
    int*   curD   = (int*)alloc((NB + 1) * 4);
    int*   offD   = (int*)alloc((NB + 1) * 4);
    int*   srcB   = (int*)alloc((size_t)E * 4);
    int*   packB  = (int*)alloc((size_t)E * 4);
    int*   rowptr = (int*)alloc((size_t)(n + 1) * 4);
    int*   csrCol = (int*)alloc((size_t)E * 4);
    float* dinv   = (float*)alloc((size_t)n * 4);
    short* buf0   = (short*)alloc((size_t)n * 128 * 2);
    short* buf1   = (short*)alloc((size_t)n * 128 * 2);
    short* buf2   = (short*)alloc((size_t)n * 128 * 2);
    short* buf3   = (short*)alloc((size_t)n * 128 * 2);
    short* Bt0    = (short*)alloc((size_t)384 * 128 * 2);
    short* Bt1    = (short*)alloc((size_t)384 * 128 * 2);
    short* Bt2    = (short*)alloc((size_t)192 * 128 * 2);

    hipMemsetAsync(binS, 0, NB * 4, stream);
    hipMemsetAsync(binD, 0, NB * 4, stream);

    const int TPB = 256;

    hist_kernel<<<512, TPB, 0, stream>>>(src, dst, binS, binD, E);
    scan_kernel<<<1, 64, 0, stream>>>(binS, binD, curS, offS, curD, offD, rowptr, E);
    int sChunks = (E + SCH - 1) / SCH;
    scatter_kernel<<<sChunks, TPB, 0, stream>>>(src, dst, curS, curD, srcB, packB, E);
    csr_kernel<<<NB, TPB, 0, stream>>>(offD, packB, rowptr, csrCol, n);
    deg_kernel<<<NB, TPB, 0, stream>>>(offS, srcB, dinv, n);

    convw_kernel<<<(122880 + 255) / 256, 256, 0, stream>>>(W0, W1, W2, Bt0, Bt1, Bt2);

    int pBlocks = (n + 3) / 4;        // 4 waves (4 nodes) per block
    int gBlocks = (n + 63) / 64;      // BM=64

    // ---- layer 1 (A = x fp32, converted at stage time) ----
    gemm_kernel<128, 1><<<gBlocks, 256, 0, stream>>>(x, Bt0, b0, buf0, buf1, buf2, n);
    prop_kernel<128, 0, 0><<<pBlocks, 256, 0, stream>>>(buf2, buf1, buf3, rowptr, csrCol, dinv, n);
    prop_kernel<128, 1, 0><<<pBlocks, 256, 0, stream>>>(buf3, buf0, buf1, rowptr, csrCol, dinv, n);
    // ---- layer 2 (Y1 in-place into buf1: own-block rows; safe) ----
    gemm_kernel<128, 0><<<gBlocks, 256, 0, stream>>>(buf1, Bt1, b1, buf0, buf1, buf2, n);
    prop_kernel<128, 0, 0><<<pBlocks, 256, 0, stream>>>(buf2, buf1, buf3, rowptr, csrCol, dinv, n);
    prop_kernel<128, 1, 0><<<pBlocks, 256, 0, stream>>>(buf3, buf0, buf1, rowptr, csrCol, dinv, n);
    // ---- layer 3: C = 64 ----
    gemm_kernel<64, 0><<<gBlocks, 256, 0, stream>>>(buf1, Bt2, b2, buf0, buf3, buf2, n);
    prop_kernel<64, 0, 0><<<pBlocks, 256, 0, stream>>>(buf2, buf3, buf0 + (size_t)n * 64,
                                                       rowptr, csrCol, dinv, n);
    prop_kernel<64, 0, 1><<<pBlocks, 256, 0, stream>>>(buf0 + (size_t)n * 64, buf0, out,
                                                       rowptr, csrCol, dinv, n);
}

// Round 14
// 498.232 us; speedup vs baseline: 1.1366x; 1.0317x over previous
//
#include <hip/hip_runtime.h>
#include <hip/hip_bf16.h>

#define NN 100000
#define NE 1600000
#define NB 196    // buckets of 512 nodes (node>>9)
#define BSH 9
#define SCH 2048  // edges per scatter chunk (782 blocks)

typedef _Float16 f16;
typedef __attribute__((ext_vector_type(2))) _Float16 h2;
typedef __attribute__((ext_vector_type(8))) _Float16 f16x8;
typedef __attribute__((ext_vector_type(8))) short short8;
typedef __attribute__((ext_vector_type(4))) float f32x4;

__device__ __forceinline__ short f16b(float x) {
    f16 h = (f16)x; short s; __builtin_memcpy(&s, &h, 2); return s;
}
__device__ __forceinline__ int h2i(h2 v) { int r; __builtin_memcpy(&r, &v, 4); return r; }
__device__ __forceinline__ h2 i2h(int v) { h2 r; __builtin_memcpy(&r, &v, 4); return r; }

// ================= graph build: counting-sort CSR =================
__global__ __launch_bounds__(256) void hist_kernel(const int* __restrict__ src,
                                                   const int* __restrict__ dst,
                                                   int* __restrict__ binS,
                                                   int* __restrict__ binD, int E) {
    __shared__ int hS[NB], hD[NB];
    for (int i = threadIdx.x; i < NB; i += 256) { hS[i] = 0; hD[i] = 0; }
    __syncthreads();
    for (int e = blockIdx.x * 256 + threadIdx.x; e < E; e += gridDim.x * 256) {
        atomicAdd(&hS[src[e] >> BSH], 1);
        atomicAdd(&hD[dst[e] >> BSH], 1);
    }
    __syncthreads();
    for (int i = threadIdx.x; i < NB; i += 256) {
        if (hS[i]) atomicAdd(&binS[i], hS[i]);
        if (hD[i]) atomicAdd(&binD[i], hD[i]);
    }
}

// parallel 196-bin dual exclusive scan (1 block, 256 threads)
__global__ __launch_bounds__(256) void scan_kernel(const int* __restrict__ binS,
                                                   const int* __restrict__ binD,
                                                   int* __restrict__ curS, int* __restrict__ offS,
                                                   int* __restrict__ curD, int* __restrict__ offD,
                                                   int* __restrict__ rowptr, int E) {
    __shared__ int sS[256], sD[256];
    int tid = threadIdx.x;
    int vS = (tid < NB) ? binS[tid] : 0;
    int vD = (tid < NB) ? binD[tid] : 0;
    sS[tid] = vS;
    sD[tid] = vD;
    __syncthreads();
    for (int off = 1; off < 256; off <<= 1) {
        int tS = (tid >= off) ? sS[tid - off] : 0;
        int tD = (tid >= off) ? sD[tid - off] : 0;
        __syncthreads();
        sS[tid] += tS;
        sD[tid] += tD;
        __syncthreads();
    }
    if (tid < NB) {
        int eS = sS[tid] - vS, eD = sD[tid] - vD;
        curS[tid] = eS; offS[tid] = eS;
        curD[tid] = eD; offD[tid] = eD;
    }
    if (tid == 0) {
        offS[NB] = sS[255];
        offD[NB] = sD[255];
        rowptr[NN] = E;
    }
}

__global__ __launch_bounds__(256) void scatter_kernel(const int* __restrict__ src,
                                                      const int* __restrict__ dst,
                                                      int* __restrict__ curS,
                                                      int* __restrict__ curD,
                                                      int* __restrict__ srcB,
                                                      int* __restrict__ packB, int E) {
    __shared__ int cS[NB], cD[NB], bS[NB], bD[NB];
    int base = blockIdx.x * SCH;
    for (int i = threadIdx.x; i < NB; i += 256) { cS[i] = 0; cD[i] = 0; }
    __syncthreads();
    int s[8], d[8], rS[8], rD[8];
#pragma unroll
    for (int k = 0; k < 8; ++k) {
        int idx = base + k * 256 + threadIdx.x;
        if (idx < E) {
            s[k] = src[idx]; d[k] = dst[idx];
            rS[k] = atomicAdd(&cS[s[k] >> BSH], 1);
            rD[k] = atomicAdd(&cD[d[k] >> BSH], 1);
        } else {
            s[k] = -1;
        }
    }
    __syncthreads();
    for (int i = threadIdx.x; i < NB; i += 256) {
        if (cS[i]) bS[i] = atomicAdd(&curS[i], cS[i]);
        if (cD[i]) bD[i] = atomicAdd(&curD[i], cD[i]);
    }
    __syncthreads();
#pragma unroll
    for (int k = 0; k < 8; ++k) {
        if (s[k] >= 0) {
            srcB[bS[s[k] >> BSH] + rS[k]] = s[k];
            packB[bD[d[k] >> BSH] + rD[k]] = s[k] | ((d[k] & 511) << 20);
        }
    }
}

// merged CSR-build (blocks 0..NB-1) + degree/dinv (blocks NB..2NB-1)
__global__ __launch_bounds__(256) void csrdeg_kernel(const int* __restrict__ offD,
                                                     const int* __restrict__ packB,
                                                     int* __restrict__ rowptr,
                                                     int* __restrict__ csrCol,
                                                     const int* __restrict__ offS,
                                                     const int* __restrict__ srcB,
                                                     float* __restrict__ dinv, int n) {
    __shared__ int h[512];
    __shared__ int roff[512];
    if (blockIdx.x < NB) {
        int b = blockIdx.x;
        int node0 = b << BSH;
        int nNodes = min(512, n - node0);
        if (nNodes <= 0) return;
        int beg = offD[b], end = offD[b + 1];
        for (int i = threadIdx.x; i < 512; i += 256) h[i] = 0;
        __syncthreads();
        for (int p = beg + threadIdx.x; p < end; p += 256)
            atomicAdd(&h[(packB[p] >> 20) & 511], 1);
        __syncthreads();
        if (threadIdx.x == 0) {
            int r = beg;
            for (int i = 0; i < 512; ++i) { roff[i] = r; r += h[i]; }
        }
        __syncthreads();
        for (int i = threadIdx.x; i < nNodes; i += 256) rowptr[node0 + i] = roff[i];
        for (int i = threadIdx.x; i < 512; i += 256) h[i] = 0;
        __syncthreads();
        for (int p = beg + threadIdx.x; p < end; p += 256) {
            int pk = packB[p];
            int dl = (pk >> 20) & 511;
            int r = atomicAdd(&h[dl], 1);
            csrCol[roff[dl] + r] = pk & 0xFFFFF;
        }
    } else {
        int b = blockIdx.x - NB;
        int node0 = b << BSH;
        int nNodes = min(512, n - node0);
        if (nNodes <= 0) return;
        int beg = offS[b], end = offS[b + 1];
        for (int i = threadIdx.x; i < 512; i += 256) h[i] = 0;
        __syncthreads();
        for (int p = beg + threadIdx.x; p < end; p += 256)
            atomicAdd(&h[srcB[p] & 511], 1);
        __syncthreads();
        for (int i = threadIdx.x; i < nNodes; i += 256) {
            int d = h[i];
            dinv[node0 + i] = d > 0 ? rsqrtf((float)d) : 0.0f;
        }
    }
}

// ================= weight prep: Bt[j][k] over j = [W0-W2 | W1 | 2*W2] cols (fp16) ========
__global__ void convw_kernel(const float* __restrict__ W0, const float* __restrict__ W1,
                             const float* __restrict__ W2, short* __restrict__ Bt0,
                             short* __restrict__ Bt1, short* __restrict__ Bt2) {
    int i = blockIdx.x * blockDim.x + threadIdx.x;
    if (i < 49152) {                       // Bt0: 384 x 128
        int j = i >> 7, k = i & 127;
        int t = j >> 7, o = j & 127;
        float v = (t == 0) ? W0[k * 128 + o] - W0[2 * 16384 + k * 128 + o]
                : (t == 1) ? W0[16384 + k * 128 + o]
                           : 2.f * W0[2 * 16384 + k * 128 + o];
        Bt0[j * 128 + k] = f16b(v);
    } else if (i < 98304) {                // Bt1: 384 x 128
        int m = i - 49152;
        int j = m >> 7, k = m & 127;
        int t = j >> 7, o = j & 127;
        float v = (t == 0) ? W1[k * 128 + o] - W1[2 * 16384 + k * 128 + o]
                : (t == 1) ? W1[16384 + k * 128 + o]
                           : 2.f * W1[2 * 16384 + k * 128 + o];
        Bt1[j * 128 + k] = f16b(v);
    } else if (i < 122880) {               // Bt2: 192 x 128
        int m = i - 98304;
        int j = m >> 7, k = m & 127;
        int t = j >> 6, o = j & 63;
        float v = (t == 0) ? W2[k * 64 + o] - W2[2 * 8192 + k * 64 + o]
                : (t == 1) ? W2[8192 + k * 64 + o]
                           : 2.f * W2[2 * 8192 + k * 64 + o];
        Bt2[j * 128 + k] = f16b(v);
    }
}

// ================= GEMM: [Y0|Y1|Y2] = A[n,128] @ Bt^T + (bias into Y0), fp16 ============
template <int C, int AF32>
__global__ __launch_bounds__(256) void gemm_kernel(const void* __restrict__ A,
                                                   const short* __restrict__ Bt,
                                                   const float* __restrict__ bias,
                                                   short* out0, short* out1, short* out2,
                                                   int n) {
    constexpr int BNT = 3 * C;
    constexpr int WC = BNT / 96;
    constexpr int WR = 4 / WC;
    constexpr int WM = 64 / WR;
    constexpr int MF = WM / 16;
    constexpr int NF = 6;
    constexpr int LDP = 40;
    constexpr int BSLOT = BNT * 4;
    constexpr int BITER = BSLOT / 256;
    __shared__ short lds[(64 + BNT) * LDP];
    short* As = lds;
    short* Bs = lds + 64 * LDP;

    int tid = threadIdx.x;
    int lane = tid & 63;
    int wid = tid >> 6;
    int wy = wid / WC;
    int wx = wid % WC;
    int row0 = blockIdx.x * 64;
    int l15 = lane & 15;
    int kb = (lane >> 4) * 8;

    int ar = tid >> 2, aseg = tid & 3;
    int agr = row0 + ar;

    f32x4 acc[MF][NF];
#pragma unroll
    for (int i = 0; i < MF; ++i)
#pragma unroll
        for (int j = 0; j < NF; ++j) acc[i][j] = (f32x4){0.f, 0.f, 0.f, 0.f};

    for (int step = 0; step < 4; ++step) {
        int k0 = step * 32;
        short8 va;
        if (AF32) {
            if (agr < n) {
                const float* xp = (const float*)A + (size_t)agr * 128 + k0 + aseg * 8;
                float4 f0 = *(const float4*)xp;
                float4 f1 = *(const float4*)(xp + 4);
                va[0] = f16b(f0.x); va[1] = f16b(f0.y); va[2] = f16b(f0.z); va[3] = f16b(f0.w);
                va[4] = f16b(f1.x); va[5] = f16b(f1.y); va[6] = f16b(f1.z); va[7] = f16b(f1.w);
            } else {
                va = (short8){0, 0, 0, 0, 0, 0, 0, 0};
            }
        } else {
            va = (agr < n)
                ? *(const short8*)((const short*)A + (size_t)agr * 128 + k0 + aseg * 8)
                : (short8){0, 0, 0, 0, 0, 0, 0, 0};
        }
        *(short8*)&As[ar * LDP + aseg * 8] = va;
#pragma unroll
        for (int i = 0; i < BITER; ++i) {
            int slot = tid + i * 256;
            int j = slot >> 2, seg = slot & 3;
            *(short8*)&Bs[j * LDP + seg * 8] =
                *(const short8*)(Bt + (size_t)j * 128 + k0 + seg * 8);
        }
        __syncthreads();
        f16x8 af[MF], bfr[NF];
#pragma unroll
        for (int mf = 0; mf < MF; ++mf)
            af[mf] = *(f16x8*)&As[(wy * WM + mf * 16 + l15) * LDP + kb];
#pragma unroll
        for (int nf = 0; nf < NF; ++nf)
            bfr[nf] = *(f16x8*)&Bs[(wx * 96 + nf * 16 + l15) * LDP + kb];
#pragma unroll
        for (int mf = 0; mf < MF; ++mf)
#pragma unroll
            for (int nf = 0; nf < NF; ++nf)
                acc[mf][nf] = __builtin_amdgcn_mfma_f32_16x16x32_f16(
                    af[mf], bfr[nf], acc[mf][nf], 0, 0, 0);
        __syncthreads();
    }

    float bb[NF];
#pragma unroll
    for (int nf = 0; nf < NF; ++nf) {
        int colc = wx * 96 + nf * 16 + l15;
        bb[nf] = (colc < C) ? bias[colc] : 0.f;
    }
    short* st = lds + wid * 1536;
#pragma unroll
    for (int mf = 0; mf < MF; ++mf) {
#pragma unroll
        for (int nf = 0; nf < NF; ++nf) {
#pragma unroll
            for (int r = 0; r < 4; ++r) {
                int fr = (lane >> 4) * 4 + r;
                st[fr * 96 + nf * 16 + l15] = f16b(acc[mf][nf][r] + bb[nf]);
            }
        }
#pragma unroll
        for (int u = 0; u < 3; ++u) {
            int unit = u * 64 + lane;
            int rr = unit / 12;
            int seg = unit - rr * 12;
            int grow = row0 + wy * WM + mf * 16 + rr;
            int colc = wx * 96 + seg * 8;
            int t = colc / C, off = colc - t * C;
            short* P = (t == 0) ? out0 : (t == 1) ? out1 : out2;
            if (grow < n)
                *(int4*)&P[(size_t)grow * C + off] = *(const int4*)&st[rr * 96 + seg * 8];
        }
    }
}

// ================= prop: O[d] = act(Add[d] - dinv[d] * sum_e dinv[s]*G[s]), packed fp16 ==
template <int C, int RELU, int OUTF>
__global__ __launch_bounds__(256) void prop_kernel(const short* __restrict__ G,
                                                   const short* __restrict__ Add,
                                                   void* __restrict__ O,
                                                   const int* __restrict__ rowptr,
                                                   const int* __restrict__ csrCol,
                                                   const float* __restrict__ dinv, int n) {
    constexpr int LPE = C / 8;
    constexpr int EPG = 64 / LPE;
    constexpr int STEP = 4 * EPG;
    int wid = (blockIdx.x * blockDim.x + threadIdx.x) >> 6;
    int lane = threadIdx.x & 63;
    if (wid >= n) return;
    int beg = rowptr[wid];
    int c = rowptr[wid + 1] - beg;
    int sg = lane / LPE;
    int sl = lane & (LPE - 1);
    h2 a0 = {0, 0}, a1 = {0, 0}, a2 = {0, 0}, a3 = {0, 0};
    for (int b0 = 0; b0 < c; b0 += 64) {
        int cb = min(64, c - b0);
        int myc = 0, mywp = 0;
        if (lane < cb) {
            myc = csrCol[beg + b0 + lane];
            f16 hw = (f16)dinv[myc];
            h2 p = {hw, hw};
            mywp = h2i(p);
        }
        for (int base = 0; base < cb; base += STEP) {
            int j0 = base + sg, j1 = j0 + EPG, j2 = j0 + 2 * EPG, j3 = j0 + 3 * EPG;
            int s0 = __shfl(myc, j0);  int w0 = __shfl(mywp, j0);
            int s1 = __shfl(myc, j1);  int w1 = __shfl(mywp, j1);
            int s2 = __shfl(myc, j2);  int w2 = __shfl(mywp, j2);
            int s3 = __shfl(myc, j3);  int w3 = __shfl(mywp, j3);
            int4 v0 = *(const int4*)(G + (size_t)s0 * C + sl * 8);
            int4 v1 = *(const int4*)(G + (size_t)s1 * C + sl * 8);
            int4 v2 = *(const int4*)(G + (size_t)s2 * C + sl * 8);
            int4 v3 = *(const int4*)(G + (size_t)s3 * C + sl * 8);
            h2 p0 = i2h(w0), p1 = i2h(w1), p2 = i2h(w2), p3 = i2h(w3);
            a0 = i2h(v0.x) * p0 + a0; a1 = i2h(v0.y) * p0 + a1;
            a2 = i2h(v0.z) * p0 + a2; a3 = i2h(v0.w) * p0 + a3;
            a0 = i2h(v1.x) * p1 + a0; a1 = i2h(v1.y) * p1 + a1;
            a2 = i2h(v1.z) * p1 + a2; a3 = i2h(v1.w) * p1 + a3;
            a0 = i2h(v2.x) * p2 + a0; a1 = i2h(v2.y) * p2 + a1;
            a2 = i2h(v2.z) * p2 + a2; a3 = i2h(v2.w) * p2 + a3;
            a0 = i2h(v3.x) * p3 + a0; a1 = i2h(v3.y) * p3 + a1;
            a2 = i2h(v3.z) * p3 + a2; a3 = i2h(v3.w) * p3 + a3;
        }
    }
#pragma unroll
    for (int off = LPE; off < 64; off <<= 1) {
        a0 += i2h(__shfl_xor(h2i(a0), off));
        a1 += i2h(__shfl_xor(h2i(a1), off));
        a2 += i2h(__shfl_xor(h2i(a2), off));
        a3 += i2h(__shfl_xor(h2i(a3), off));
    }
    if (lane < LPE) {
        float scale = -dinv[wid];
        int4 ad = *(const int4*)(Add + (size_t)wid * C + sl * 8);
        h2 d0 = i2h(ad.x), d1 = i2h(ad.y), d2 = i2h(ad.z), d3 = i2h(ad.w);
        float r0 = fmaf(scale, (float)a0[0], (float)d0[0]);
        float r1 = fmaf(scale, (float)a0[1], (float)d0[1]);
        float r2 = fmaf(scale, (float)a1[0], (float)d1[0]);
        float r3 = fmaf(scale, (float)a1[1], (float)d1[1]);
        float r4 = fmaf(scale, (float)a2[0], (float)d2[0]);
        float r5 = fmaf(scale, (float)a2[1], (float)d2[1]);
        float r6 = fmaf(scale, (float)a3[0], (float)d3[0]);
        float r7 = fmaf(scale, (float)a3[1], (float)d3[1]);
        if (RELU) {
            r0 = fmaxf(r0, 0.f); r1 = fmaxf(r1, 0.f); r2 = fmaxf(r2, 0.f);
            r3 = fmaxf(r3, 0.f); r4 = fmaxf(r4, 0.f); r5 = fmaxf(r5, 0.f);
            r6 = fmaxf(r6, 0.f); r7 = fmaxf(r7, 0.f);
        }
        if (OUTF) {
            float* op = (float*)O + (size_t)wid * C + sl * 8;
            *(float4*)op = make_float4(r0, r1, r2, r3);
            *(float4*)(op + 4) = make_float4(r4, r5, r6, r7);
        } else {
            int4 w;
            h2 o0 = {(f16)r0, (f16)r1}, o1 = {(f16)r2, (f16)r3};
            h2 o2 = {(f16)r4, (f16)r5}, o3 = {(f16)r6, (f16)r7};
            w.x = h2i(o0); w.y = h2i(o1); w.z = h2i(o2); w.w = h2i(o3);
            *(int4*)((short*)O + (size_t)wid * C + sl * 8) = w;
        }
    }
}

extern "C" void kernel_launch(void* const* d_in, const int* in_sizes, int n_in,
                              void* d_out, int out_size, void* d_ws, size_t ws_size,
                              hipStream_t stream) {
    const float* x  = (const float*)d_in[0];
    const int*   ei = (const int*)d_in[1];
    const float* W0 = (const float*)d_in[2];
    const float* b0 = (const float*)d_in[3];
    const float* W1 = (const float*)d_in[4];
    const float* b1 = (const float*)d_in[5];
    const float* W2 = (const float*)d_in[6];
    const float* b2 = (const float*)d_in[7];
    float* out = (float*)d_out;

    const int n = NN, E = NE;
    const int* src = ei;
    const int* dst = ei + E;

    char* ws = (char*)d_ws;
    auto alloc = [&](size_t bytes) -> void* {
        void* p = (void*)ws;
        ws += (bytes + 255) & ~(size_t)255;
        return p;
    };
    int*   binS   = (int*)alloc(NB * 4);
    int*   binD   = (int*)alloc(NB * 4);
    int*   curS   = (int*)alloc((NB + 1) * 4);
    int*   offS   = (int*)alloc((NB + 1) * 4);
    int*   curD   = (int*)alloc((NB + 1) * 4);
    int*   offD   = (int*)alloc((NB + 1) * 4);
    int*   srcB   = (int*)alloc((size_t)E * 4);
    int*   packB  = (int*)alloc((size_t)E * 4);
    int*   rowptr = (int*)alloc((size_t)(n + 1) * 4);
    int*   csrCol = (int*)alloc((size_t)E * 4);
    float* dinv   = (float*)alloc((size_t)n * 4);
    short* buf0   = (short*)alloc((size_t)n * 128 * 2);
    short* buf1   = (short*)alloc((size_t)n * 128 * 2);
    short* buf2   = (short*)alloc((size_t)n * 128 * 2);
    short* buf3   = (short*)alloc((size_t)n * 128 * 2);
    short* Bt0    = (short*)alloc((size_t)384 * 128 * 2);
    short* Bt1    = (short*)alloc((size_t)384 * 128 * 2);
    short* Bt2    = (short*)alloc((size_t)192 * 128 * 2);

    hipMemsetAsync(binS, 0, NB * 4, stream);
    hipMemsetAsync(binD, 0, NB * 4, stream);

    const int TPB = 256;

    hist_kernel<<<512, TPB, 0, stream>>>(src, dst, binS, binD, E);
    scan_kernel<<<1, 256, 0, stream>>>(binS, binD, curS, offS, curD, offD, rowptr, E);
    int sChunks = (E + SCH - 1) / SCH;
    scatter_kernel<<<sChunks, TPB, 0, stream>>>(src, dst, curS, curD, srcB, packB, E);
    csrdeg_kernel<<<2 * NB, TPB, 0, stream>>>(offD, packB, rowptr, csrCol,
                                              offS, srcB, dinv, n);

    convw_kernel<<<(122880 + 255) / 256, 256, 0, stream>>>(W0, W1, W2, Bt0, Bt1, Bt2);

    int pBlocks = (n + 3) / 4;        // 4 waves (4 nodes) per block
    int gBlocks = (n + 63) / 64;      // BM=64

    // ---- layer 1 (A = x fp32, converted at stage time) ----
    gemm_kernel<128, 1><<<gBlocks, 256, 0, stream>>>(x, Bt0, b0, buf0, buf1, buf2, n);
    prop_kernel<128, 0, 0><<<pBlocks, 256, 0, stream>>>(buf2, buf1, buf3, rowptr, csrCol, dinv, n);
    prop_kernel<128, 1, 0><<<pBlocks, 256, 0, stream>>>(buf3, buf0, buf1, rowptr, csrCol, dinv, n);
    // ---- layer 2 (Y1 in-place into buf1: own-block rows; safe) ----
    gemm_kernel<128, 0><<<gBlocks, 256, 0, stream>>>(buf1, Bt1, b1, buf0, buf1, buf2, n);
    prop_kernel<128, 0, 0><<<pBlocks, 256, 0, stream>>>(buf2, buf1, buf3, rowptr, csrCol, dinv, n);
    prop_kernel<128, 1, 0><<<pBlocks, 256, 0, stream>>>(buf3, buf0, buf1, rowptr, csrCol, dinv, n);
    // ---- layer 3: C = 64 ----
    gemm_kernel<64, 0><<<gBlocks, 256, 0, stream>>>(buf1, Bt2, b2, buf0, buf3, buf2, n);
    prop_kernel<64, 0, 0><<<pBlocks, 256, 0, stream>>>(buf2, buf3, buf0 + (size_t)n * 64,
                                                       rowptr, csrCol, dinv, n);
    prop_kernel<64, 0, 1><<<pBlocks, 256, 0, stream>>>(buf0 + (size_t)n * 64, buf0, out,
                                                       rowptr, csrCol, dinv, n);
}

// Round 15
// 484.905 us; speedup vs baseline: 1.1678x; 1.0275x over previous
//
#include <hip/hip_runtime.h>
#include <hip/hip_bf16.h>

#define NN 100000
#define NE 1600000
#define NB 196    // buckets of 512 nodes (node>>9)
#define BSH 9
#define SCH 2048  // edges per scatter chunk (782 blocks)

typedef _Float16 f16;
typedef __attribute__((ext_vector_type(2))) _Float16 h2;
typedef __attribute__((ext_vector_type(8))) _Float16 f16x8;
typedef __attribute__((ext_vector_type(8))) short short8;
typedef __attribute__((ext_vector_type(4))) float f32x4;

__device__ __forceinline__ short f16b(float x) {
    f16 h = (f16)x; short s; __builtin_memcpy(&s, &h, 2); return s;
}
__device__ __forceinline__ int h2i(h2 v) { int r; __builtin_memcpy(&r, &v, 4); return r; }
__device__ __forceinline__ h2 i2h(int v) { h2 r; __builtin_memcpy(&r, &v, 4); return r; }

// ================= K1: histogram (blocks 0..511) + weight conv (blocks 512..991) =========
__global__ __launch_bounds__(256) void histconv_kernel(const int* __restrict__ src,
                                                       const int* __restrict__ dst,
                                                       int* __restrict__ binS,
                                                       int* __restrict__ binD, int E,
                                                       const float* __restrict__ W0,
                                                       const float* __restrict__ W1,
                                                       const float* __restrict__ W2,
                                                       short* __restrict__ Bt0,
                                                       short* __restrict__ Bt1,
                                                       short* __restrict__ Bt2) {
    if (blockIdx.x < 512) {
        __shared__ int hS[NB], hD[NB];
        for (int i = threadIdx.x; i < NB; i += 256) { hS[i] = 0; hD[i] = 0; }
        __syncthreads();
        for (int e = blockIdx.x * 256 + threadIdx.x; e < E; e += 512 * 256) {
            atomicAdd(&hS[src[e] >> BSH], 1);
            atomicAdd(&hD[dst[e] >> BSH], 1);
        }
        __syncthreads();
        for (int i = threadIdx.x; i < NB; i += 256) {
            if (hS[i]) atomicAdd(&binS[i], hS[i]);
            if (hD[i]) atomicAdd(&binD[i], hD[i]);
        }
    } else {
        int i = (blockIdx.x - 512) * 256 + threadIdx.x;
        if (i < 49152) {                       // Bt0: 384 x 128
            int j = i >> 7, k = i & 127;
            int t = j >> 7, o = j & 127;
            float v = (t == 0) ? W0[k * 128 + o] - W0[2 * 16384 + k * 128 + o]
                    : (t == 1) ? W0[16384 + k * 128 + o]
                               : 2.f * W0[2 * 16384 + k * 128 + o];
            Bt0[j * 128 + k] = f16b(v);
        } else if (i < 98304) {                // Bt1: 384 x 128
            int m = i - 49152;
            int j = m >> 7, k = m & 127;
            int t = j >> 7, o = j & 127;
            float v = (t == 0) ? W1[k * 128 + o] - W1[2 * 16384 + k * 128 + o]
                    : (t == 1) ? W1[16384 + k * 128 + o]
                               : 2.f * W1[2 * 16384 + k * 128 + o];
            Bt1[j * 128 + k] = f16b(v);
        } else if (i < 122880) {               // Bt2: 192 x 128
            int m = i - 98304;
            int j = m >> 7, k = m & 127;
            int t = j >> 6, o = j & 63;
            float v = (t == 0) ? W2[k * 64 + o] - W2[2 * 8192 + k * 64 + o]
                    : (t == 1) ? W2[8192 + k * 64 + o]
                               : 2.f * W2[2 * 8192 + k * 64 + o];
            Bt2[j * 128 + k] = f16b(v);
        }
    }
}

// ================= K2: parallel 196-bin dual exclusive scan =================
__global__ __launch_bounds__(256) void scan_kernel(const int* __restrict__ binS,
                                                   const int* __restrict__ binD,
                                                   int* __restrict__ curS, int* __restrict__ offS,
                                                   int* __restrict__ curD, int* __restrict__ offD,
                                                   int* __restrict__ rowptr, int E) {
    __shared__ int sS[256], sD[256];
    int tid = threadIdx.x;
    int vS = (tid < NB) ? binS[tid] : 0;
    int vD = (tid < NB) ? binD[tid] : 0;
    sS[tid] = vS;
    sD[tid] = vD;
    __syncthreads();
    for (int off = 1; off < 256; off <<= 1) {
        int tS = (tid >= off) ? sS[tid - off] : 0;
        int tD = (tid >= off) ? sD[tid - off] : 0;
        __syncthreads();
        sS[tid] += tS;
        sD[tid] += tD;
        __syncthreads();
    }
    if (tid < NB) {
        int eS = sS[tid] - vS, eD = sD[tid] - vD;
        curS[tid] = eS; offS[tid] = eS;
        curD[tid] = eD; offD[tid] = eD;
    }
    if (tid == 0) {
        offS[NB] = sS[255];
        offD[NB] = sD[255];
        rowptr[NN] = E;
    }
}

// ================= K3: dual scatter into buckets =================
__global__ __launch_bounds__(256) void scatter_kernel(const int* __restrict__ src,
                                                      const int* __restrict__ dst,
                                                      int* __restrict__ curS,
                                                      int* __restrict__ curD,
                                                      int* __restrict__ srcB,
                                                      int* __restrict__ packB, int E) {
    __shared__ int cS[NB], cD[NB], bS[NB], bD[NB];
    int base = blockIdx.x * SCH;
    for (int i = threadIdx.x; i < NB; i += 256) { cS[i] = 0; cD[i] = 0; }
    __syncthreads();
    int s[8], d[8], rS[8], rD[8];
#pragma unroll
    for (int k = 0; k < 8; ++k) {
        int idx = base + k * 256 + threadIdx.x;
        if (idx < E) {
            s[k] = src[idx]; d[k] = dst[idx];
            rS[k] = atomicAdd(&cS[s[k] >> BSH], 1);
            rD[k] = atomicAdd(&cD[d[k] >> BSH], 1);
        } else {
            s[k] = -1;
        }
    }
    __syncthreads();
    for (int i = threadIdx.x; i < NB; i += 256) {
        if (cS[i]) bS[i] = atomicAdd(&curS[i], cS[i]);
        if (cD[i]) bD[i] = atomicAdd(&curD[i], cD[i]);
    }
    __syncthreads();
#pragma unroll
    for (int k = 0; k < 8; ++k) {
        if (s[k] >= 0) {
            srcB[bS[s[k] >> BSH] + rS[k]] = s[k];
            packB[bD[d[k] >> BSH] + rD[k]] = s[k] | ((d[k] & 511) << 20);
        }
    }
}

// ================= K4: CSR-build + degree (blocks 0..2NB-1) + layer-1 GEMM (rest) ========
__global__ __launch_bounds__(256) void csrdeg_gemm_kernel(const int* __restrict__ offD,
                                                          const int* __restrict__ packB,
                                                          int* __restrict__ rowptr,
                                                          int* __restrict__ csrCol,
                                                          const int* __restrict__ offS,
                                                          const int* __restrict__ srcB,
                                                          float* __restrict__ dinv,
                                                          const float* __restrict__ x,
                                                          const short* __restrict__ Bt,
                                                          const float* __restrict__ bias,
                                                          short* out0, short* out1,
                                                          short* out2, int n) {
    __shared__ short lds[(64 + 384) * 40];   // 35840 B; csrdeg path reuses the front 4 KB
    if (blockIdx.x < 2 * NB) {
        int* h = (int*)lds;
        int* roff = h + 512;
        if (blockIdx.x < NB) {
            int b = blockIdx.x;
            int node0 = b << BSH;
            int nNodes = min(512, n - node0);
            if (nNodes <= 0) return;
            int beg = offD[b], end = offD[b + 1];
            for (int i = threadIdx.x; i < 512; i += 256) h[i] = 0;
            __syncthreads();
            for (int p = beg + threadIdx.x; p < end; p += 256)
                atomicAdd(&h[(packB[p] >> 20) & 511], 1);
            __syncthreads();
            if (threadIdx.x == 0) {
                int r = beg;
                for (int i = 0; i < 512; ++i) { roff[i] = r; r += h[i]; }
            }
            __syncthreads();
            for (int i = threadIdx.x; i < nNodes; i += 256) rowptr[node0 + i] = roff[i];
            for (int i = threadIdx.x; i < 512; i += 256) h[i] = 0;
            __syncthreads();
            for (int p = beg + threadIdx.x; p < end; p += 256) {
                int pk = packB[p];
                int dl = (pk >> 20) & 511;
                int r = atomicAdd(&h[dl], 1);
                csrCol[roff[dl] + r] = pk & 0xFFFFF;
            }
        } else {
            int b = blockIdx.x - NB;
            int node0 = b << BSH;
            int nNodes = min(512, n - node0);
            if (nNodes <= 0) return;
            int beg = offS[b], end = offS[b + 1];
            for (int i = threadIdx.x; i < 512; i += 256) h[i] = 0;
            __syncthreads();
            for (int p = beg + threadIdx.x; p < end; p += 256)
                atomicAdd(&h[srcB[p] & 511], 1);
            __syncthreads();
            for (int i = threadIdx.x; i < nNodes; i += 256) {
                int d = h[i];
                dinv[node0 + i] = d > 0 ? rsqrtf((float)d) : 0.0f;
            }
        }
        return;
    }
    // ---- layer-1 GEMM path: C=128, A = x (fp32 -> fp16 at stage) ----
    constexpr int LDP = 40;
    short* As = lds;
    short* Bs = lds + 64 * LDP;
    int tid = threadIdx.x;
    int lane = tid & 63;
    int wid = tid >> 6;
    int wy = 0;                 // WR=1
    int wx = wid;               // WC=4
    int row0 = (blockIdx.x - 2 * NB) * 64;
    int l15 = lane & 15;
    int kb = (lane >> 4) * 8;
    int ar = tid >> 2, aseg = tid & 3;
    int agr = row0 + ar;

    f32x4 acc[4][6];
#pragma unroll
    for (int i = 0; i < 4; ++i)
#pragma unroll
        for (int j = 0; j < 6; ++j) acc[i][j] = (f32x4){0.f, 0.f, 0.f, 0.f};

    for (int step = 0; step < 4; ++step) {
        int k0 = step * 32;
        short8 va;
        if (agr < n) {
            const float* xp = x + (size_t)agr * 128 + k0 + aseg * 8;
            float4 f0 = *(const float4*)xp;
            float4 f1 = *(const float4*)(xp + 4);
            va[0] = f16b(f0.x); va[1] = f16b(f0.y); va[2] = f16b(f0.z); va[3] = f16b(f0.w);
            va[4] = f16b(f1.x); va[5] = f16b(f1.y); va[6] = f16b(f1.z); va[7] = f16b(f1.w);
        } else {
            va = (short8){0, 0, 0, 0, 0, 0, 0, 0};
        }
        *(short8*)&As[ar * LDP + aseg * 8] = va;
#pragma unroll
        for (int i = 0; i < 6; ++i) {
            int slot = tid + i * 256;
            int j = slot >> 2, seg = slot & 3;
            *(short8*)&Bs[j * LDP + seg * 8] =
                *(const short8*)(Bt + (size_t)j * 128 + k0 + seg * 8);
        }
        __syncthreads();
        f16x8 af[4], bfr[6];
#pragma unroll
        for (int mf = 0; mf < 4; ++mf)
            af[mf] = *(f16x8*)&As[(mf * 16 + l15) * LDP + kb];
#pragma unroll
        for (int nf = 0; nf < 6; ++nf)
            bfr[nf] = *(f16x8*)&Bs[(wx * 96 + nf * 16 + l15) * LDP + kb];
#pragma unroll
        for (int mf = 0; mf < 4; ++mf)
#pragma unroll
            for (int nf = 0; nf < 6; ++nf)
                acc[mf][nf] = __builtin_amdgcn_mfma_f32_16x16x32_f16(
                    af[mf], bfr[nf], acc[mf][nf], 0, 0, 0);
        __syncthreads();
    }
    float bb[6];
#pragma unroll
    for (int nf = 0; nf < 6; ++nf) {
        int colc = wx * 96 + nf * 16 + l15;
        bb[nf] = (colc < 128) ? bias[colc] : 0.f;
    }
    short* st = lds + wid * 1536;
#pragma unroll
    for (int mf = 0; mf < 4; ++mf) {
#pragma unroll
        for (int nf = 0; nf < 6; ++nf) {
#pragma unroll
            for (int r = 0; r < 4; ++r) {
                int fr = (lane >> 4) * 4 + r;
                st[fr * 96 + nf * 16 + l15] = f16b(acc[mf][nf][r] + bb[nf]);
            }
        }
#pragma unroll
        for (int u = 0; u < 3; ++u) {
            int unit = u * 64 + lane;
            int rr = unit / 12;
            int seg = unit - rr * 12;
            int grow = row0 + mf * 16 + rr;
            int colc = wx * 96 + seg * 8;
            int t = colc >> 7, off = colc & 127;
            short* P = (t == 0) ? out0 : (t == 1) ? out1 : out2;
            if (grow < n)
                *(int4*)&P[(size_t)grow * 128 + off] = *(const int4*)&st[rr * 96 + seg * 8];
        }
    }
}

// ================= GEMM (layers 2/3): [Y0|Y1|Y2] = A[n,128] @ Bt^T (+bias into Y0) ======
template <int C>
__global__ __launch_bounds__(256) void gemm_kernel(const short* __restrict__ A,
                                                   const short* __restrict__ Bt,
                                                   const float* __restrict__ bias,
                                                   short* out0, short* out1, short* out2,
                                                   int n) {
    constexpr int BNT = 3 * C;
    constexpr int WC = BNT / 96;
    constexpr int WR = 4 / WC;
    constexpr int WM = 64 / WR;
    constexpr int MF = WM / 16;
    constexpr int NF = 6;
    constexpr int LDP = 40;
    constexpr int BSLOT = BNT * 4;
    constexpr int BITER = BSLOT / 256;
    __shared__ short lds[(64 + BNT) * LDP];
    short* As = lds;
    short* Bs = lds + 64 * LDP;

    int tid = threadIdx.x;
    int lane = tid & 63;
    int wid = tid >> 6;
    int wy = wid / WC;
    int wx = wid % WC;
    int row0 = blockIdx.x * 64;
    int l15 = lane & 15;
    int kb = (lane >> 4) * 8;
    int ar = tid >> 2, aseg = tid & 3;
    int agr = row0 + ar;

    f32x4 acc[MF][NF];
#pragma unroll
    for (int i = 0; i < MF; ++i)
#pragma unroll
        for (int j = 0; j < NF; ++j) acc[i][j] = (f32x4){0.f, 0.f, 0.f, 0.f};

    for (int step = 0; step < 4; ++step) {
        int k0 = step * 32;
        short8 va = (agr < n)
            ? *(const short8*)(A + (size_t)agr * 128 + k0 + aseg * 8)
            : (short8){0, 0, 0, 0, 0, 0, 0, 0};
        *(short8*)&As[ar * LDP + aseg * 8] = va;
#pragma unroll
        for (int i = 0; i < BITER; ++i) {
            int slot = tid + i * 256;
            int j = slot >> 2, seg = slot & 3;
            *(short8*)&Bs[j * LDP + seg * 8] =
                *(const short8*)(Bt + (size_t)j * 128 + k0 + seg * 8);
        }
        __syncthreads();
        f16x8 af[MF], bfr[NF];
#pragma unroll
        for (int mf = 0; mf < MF; ++mf)
            af[mf] = *(f16x8*)&As[(wy * WM + mf * 16 + l15) * LDP + kb];
#pragma unroll
        for (int nf = 0; nf < NF; ++nf)
            bfr[nf] = *(f16x8*)&Bs[(wx * 96 + nf * 16 + l15) * LDP + kb];
#pragma unroll
        for (int mf = 0; mf < MF; ++mf)
#pragma unroll
            for (int nf = 0; nf < NF; ++nf)
                acc[mf][nf] = __builtin_amdgcn_mfma_f32_16x16x32_f16(
                    af[mf], bfr[nf], acc[mf][nf], 0, 0, 0);
        __syncthreads();
    }

    float bb[NF];
#pragma unroll
    for (int nf = 0; nf < NF; ++nf) {
        int colc = wx * 96 + nf * 16 + l15;
        bb[nf] = (colc < C) ? bias[colc] : 0.f;
    }
    short* st = lds + wid * 1536;
#pragma unroll
    for (int mf = 0; mf < MF; ++mf) {
#pragma unroll
        for (int nf = 0; nf < NF; ++nf) {
#pragma unroll
            for (int r = 0; r < 4; ++r) {
                int fr = (lane >> 4) * 4 + r;
                st[fr * 96 + nf * 16 + l15] = f16b(acc[mf][nf][r] + bb[nf]);
            }
        }
#pragma unroll
        for (int u = 0; u < 3; ++u) {
            int unit = u * 64 + lane;
            int rr = unit / 12;
            int seg = unit - rr * 12;
            int grow = row0 + wy * WM + mf * 16 + rr;
            int colc = wx * 96 + seg * 8;
            int t = colc / C, off = colc - t * C;
            short* P = (t == 0) ? out0 : (t == 1) ? out1 : out2;
            if (grow < n)
                *(int4*)&P[(size_t)grow * C + off] = *(const int4*)&st[rr * 96 + seg * 8];
        }
    }
}

// ================= prop: O[d] = act(Add[d] - dinv[d] * sum_e dinv[s]*G[s]), packed fp16 ==
template <int C, int RELU, int OUTF>
__global__ __launch_bounds__(256) void prop_kernel(const short* __restrict__ G,
                                                   const short* __restrict__ Add,
                                                   void* __restrict__ O,
                                                   const int* __restrict__ rowptr,
                                                   const int* __restrict__ csrCol,
                                                   const float* __restrict__ dinv, int n) {
    constexpr int LPE = C / 8;
    constexpr int EPG = 64 / LPE;
    constexpr int STEP = 4 * EPG;
    int wid = (blockIdx.x * blockDim.x + threadIdx.x) >> 6;
    int lane = threadIdx.x & 63;
    if (wid >= n) return;
    int beg = rowptr[wid];
    int c = rowptr[wid + 1] - beg;
    int sg = lane / LPE;
    int sl = lane & (LPE - 1);
    h2 a0 = {0, 0}, a1 = {0, 0}, a2 = {0, 0}, a3 = {0, 0};
    for (int b0 = 0; b0 < c; b0 += 64) {
        int cb = min(64, c - b0);
        int myc = 0, mywp = 0;
        if (lane < cb) {
            myc = csrCol[beg + b0 + lane];
            f16 hw = (f16)dinv[myc];
            h2 p = {hw, hw};
            mywp = h2i(p);
        }
        for (int base = 0; base < cb; base += STEP) {
            int j0 = base + sg, j1 = j0 + EPG, j2 = j0 + 2 * EPG, j3 = j0 + 3 * EPG;
            int s0 = __shfl(myc, j0);  int w0 = __shfl(mywp, j0);
            int s1 = __shfl(myc, j1);  int w1 = __shfl(mywp, j1);
            int s2 = __shfl(myc, j2);  int w2 = __shfl(mywp, j2);
            int s3 = __shfl(myc, j3);  int w3 = __shfl(mywp, j3);
            int4 v0 = *(const int4*)(G + (size_t)s0 * C + sl * 8);
            int4 v1 = *(const int4*)(G + (size_t)s1 * C + sl * 8);
            int4 v2 = *(const int4*)(G + (size_t)s2 * C + sl * 8);
            int4 v3 = *(const int4*)(G + (size_t)s3 * C + sl * 8);
            h2 p0 = i2h(w0), p1 = i2h(w1), p2 = i2h(w2), p3 = i2h(w3);
            a0 = i2h(v0.x) * p0 + a0; a1 = i2h(v0.y) * p0 + a1;
            a2 = i2h(v0.z) * p0 + a2; a3 = i2h(v0.w) * p0 + a3;
            a0 = i2h(v1.x) * p1 + a0; a1 = i2h(v1.y) * p1 + a1;
            a2 = i2h(v1.z) * p1 + a2; a3 = i2h(v1.w) * p1 + a3;
            a0 = i2h(v2.x) * p2 + a0; a1 = i2h(v2.y) * p2 + a1;
            a2 = i2h(v2.z) * p2 + a2; a3 = i2h(v2.w) * p2 + a3;
            a0 = i2h(v3.x) * p3 + a0; a1 = i2h(v3.y) * p3 + a1;
            a2 = i2h(v3.z) * p3 + a2; a3 = i2h(v3.w) * p3 + a3;
        }
    }
#pragma unroll
    for (int off = LPE; off < 64; off <<= 1) {
        a0 += i2h(__shfl_xor(h2i(a0), off));
        a1 += i2h(__shfl_xor(h2i(a1), off));
        a2 += i2h(__shfl_xor(h2i(a2), off));
        a3 += i2h(__shfl_xor(h2i(a3), off));
    }
    if (lane < LPE) {
        float scale = -dinv[wid];
        int4 ad = *(const int4*)(Add + (size_t)wid * C + sl * 8);
        h2 d0 = i2h(ad.x), d1 = i2h(ad.y), d2 = i2h(ad.z), d3 = i2h(ad.w);
        float r0 = fmaf(scale, (float)a0[0], (float)d0[0]);
        float r1 = fmaf(scale, (float)a0[1], (float)d0[1]);
        float r2 = fmaf(scale, (float)a1[0], (float)d1[0]);
        float r3 = fmaf(scale, (float)a1[1], (float)d1[1]);
        float r4 = fmaf(scale, (float)a2[0], (float)d2[0]);
        float r5 = fmaf(scale, (float)a2[1], (float)d2[1]);
        float r6 = fmaf(scale, (float)a3[0], (float)d3[0]);
        float r7 = fmaf(scale, (float)a3[1], (float)d3[1]);
        if (RELU) {
            r0 = fmaxf(r0, 0.f); r1 = fmaxf(r1, 0.f); r2 = fmaxf(r2, 0.f);
            r3 = fmaxf(r3, 0.f); r4 = fmaxf(r4, 0.f); r5 = fmaxf(r5, 0.f);
            r6 = fmaxf(r6, 0.f); r7 = fmaxf(r7, 0.f);
        }
        if (OUTF) {
            float* op = (float*)O + (size_t)wid * C + sl * 8;
            *(float4*)op = make_float4(r0, r1, r2, r3);
            *(float4*)(op + 4) = make_float4(r4, r5, r6, r7);
        } else {
            int4 w;
            h2 o0 = {(f16)r0, (f16)r1}, o1 = {(f16)r2, (f16)r3};
            h2 o2 = {(f16)r4, (f16)r5}, o3 = {(f16)r6, (f16)r7};
            w.x = h2i(o0); w.y = h2i(o1); w.z = h2i(o2); w.w = h2i(o3);
            *(int4*)((short*)O + (size_t)wid * C + sl * 8) = w;
        }
    }
}

extern "C" void kernel_launch(void* const* d_in, const int* in_sizes, int n_in,
                              void* d_out, int out_size, void* d_ws, size_t ws_size,
                              hipStream_t stream) {
    const float* x  = (const float*)d_in[0];
    const int*   ei = (const int*)d_in[1];
    const float* W0 = (const float*)d_in[2];
    const float* b0 = (const float*)d_in[3];
    const float* W1 = (const float*)d_in[4];
    const float* b1 = (const float*)d_in[5];
    const float* W2 = (const float*)d_in[6];
    const float* b2 = (const float*)d_in[7];
    float* out = (float*)d_out;

    const int n = NN, E = NE;
    const int* src = ei;
    const int* dst = ei + E;

    char* ws = (char*)d_ws;
    auto alloc = [&](size_t bytes) -> void* {
        void* p = (void*)ws;
        ws += (bytes + 255) & ~(size_t)255;
        return p;
    };
    int*   binSD  = (int*)alloc(2 * NB * 4);   // binS | binD contiguous (one memset)
    int*   binS   = binSD;
    int*   binD   = binSD + NB;
    int*   curS   = (int*)alloc((NB + 1) * 4);
    int*   offS   = (int*)alloc((NB + 1) * 4);
    int*   curD   = (int*)alloc((NB + 1) * 4);
    int*   offD   = (int*)alloc((NB + 1) * 4);
    int*   srcB   = (int*)alloc((size_t)E * 4);
    int*   packB  = (int*)alloc((size_t)E * 4);
    int*   rowptr = (int*)alloc((size_t)(n + 1) * 4);
    int*   csrCol = (int*)alloc((size_t)E * 4);
    float* dinv   = (float*)alloc((size_t)n * 4);
    short* buf0   = (short*)alloc((size_t)n * 128 * 2);
    short* buf1   = (short*)alloc((size_t)n * 128 * 2);
    short* buf2   = (short*)alloc((size_t)n * 128 * 2);
    short* buf3   = (short*)alloc((size_t)n * 128 * 2);
    short* Bt0    = (short*)alloc((size_t)384 * 128 * 2);
    short* Bt1    = (short*)alloc((size_t)384 * 128 * 2);
    short* Bt2    = (short*)alloc((size_t)192 * 128 * 2);

    hipMemsetAsync(binSD, 0, 2 * NB * 4, stream);

    const int TPB = 256;

    histconv_kernel<<<992, TPB, 0, stream>>>(src, dst, binS, binD, E,
                                             W0, W1, W2, Bt0, Bt1, Bt2);
    scan_kernel<<<1, 256, 0, stream>>>(binS, binD, curS, offS, curD, offD, rowptr, E);
    int sChunks = (E + SCH - 1) / SCH;
    scatter_kernel<<<sChunks, TPB, 0, stream>>>(src, dst, curS, curD, srcB, packB, E);

    int gBlocks = (n + 63) / 64;      // 1563
    int pBlocks = (n + 3) / 4;

    // CSR+deg+layer-1 GEMM in one fat launch
    csrdeg_gemm_kernel<<<2 * NB + gBlocks, TPB, 0, stream>>>(
        offD, packB, rowptr, csrCol, offS, srcB, dinv,
        x, Bt0, b0, buf0, buf1, buf2, n);

    // ---- layer 1 props ----
    prop_kernel<128, 0, 0><<<pBlocks, 256, 0, stream>>>(buf2, buf1, buf3, rowptr, csrCol, dinv, n);
    prop_kernel<128, 1, 0><<<pBlocks, 256, 0, stream>>>(buf3, buf0, buf1, rowptr, csrCol, dinv, n);
    // ---- layer 2 (Y1 in-place into buf1: own-block rows; safe) ----
    gemm_kernel<128><<<gBlocks, 256, 0, stream>>>(buf1, Bt1, b1, buf0, buf1, buf2, n);
    prop_kernel<128, 0, 0><<<pBlocks, 256, 0, stream>>>(buf2, buf1, buf3, rowptr, csrCol, dinv, n);
    prop_kernel<128, 1, 0><<<pBlocks, 256, 0, stream>>>(buf3, buf0, buf1, rowptr, csrCol, dinv, n);
    // ---- layer 3: C = 64 ----
    gemm_kernel<64><<<gBlocks, 256, 0, stream>>>(buf1, Bt2, b2, buf0, buf3, buf2, n);
    prop_kernel<64, 0, 0><<<pBlocks, 256, 0, stream>>>(buf2, buf3, buf0 + (size_t)n * 64,
                                                       rowptr, csrCol, dinv, n);
    prop_kernel<64, 0, 1><<<pBlocks, 256, 0, stream>>>(buf0 + (size_t)n * 64, buf0, out,
                                                       rowptr, csrCol, dinv, n);
}